// Round 11
// baseline (1199.957 us; speedup 1.0000x reference)
//
#include <hip/hip_runtime.h>
#include <cstdint>
#include <cstddef>

#define NB 64      // batch
#define LN 48      // buffer length
#define DN 256     // hidden dim
#define TKN 128    // tracker dim
#define TN 95      // steps
#define RMAX 48    // max reduces per batch
#define GA 512     // 4*TK
#define GR 1280    // 5*D
#define NWG 256
#define NT 512

__device__ __forceinline__ float sigf(float x) { return 1.0f / (1.0f + expf(-x)); }

__device__ __forceinline__ float bf2f(unsigned u16) {
    unsigned x = u16 << 16;
    return __builtin_bit_cast(float, x);
}
__device__ __forceinline__ unsigned short f2bf(float f) {
    unsigned x = __builtin_bit_cast(unsigned, f);
    unsigned r = (x + 0x7FFFu + ((x >> 16) & 1u)) >> 16;
    return (unsigned short)r;
}

// coherent (sc1) access — bypasses non-coherent per-XCD L2 (verified r4-r10)
__device__ __forceinline__ float cohLd(const float* p) {
    return __hip_atomic_load(p, __ATOMIC_RELAXED, __HIP_MEMORY_SCOPE_AGENT);
}
__device__ __forceinline__ void cohSt(float* p, float v) {
    __hip_atomic_store(p, v, __ATOMIC_RELAXED, __HIP_MEMORY_SCOPE_AGENT);
}
__device__ __forceinline__ unsigned cohLdU(const unsigned* p) {
    return __hip_atomic_load(p, __ATOMIC_RELAXED, __HIP_MEMORY_SCOPE_AGENT);
}
__device__ __forceinline__ void cohStU(unsigned* p, unsigned v) {
    __hip_atomic_store(p, v, __ATOMIC_RELAXED, __HIP_MEMORY_SCOPE_AGENT);
}

// ---------------- schedule builder (verified r1-r10) ------------------------
__global__ void k_sched(const int* __restrict__ trans,
                        int* __restrict__ tbcode, int* __restrict__ s1code,
                        int* __restrict__ s2code, int* __restrict__ wkA,
                        int* __restrict__ fcode, int* __restrict__ anyred) {
    __shared__ int tg[NB][LN];
    int b = threadIdx.x;
    if (b >= NB) return;
    for (int i = 0; i < LN; ++i) tg[b][i] = -1;
    int sp = 0, bp = 0, k = 0;
    for (int t = 0; t < TN; ++t) {
        int tr = trans[b * TN + t];
        int shift = (tr == 0);
        int tb = (bp < LN) ? bp : -1;
        tbcode[t * NB + b] = tb;
        int i1 = sp - 1; if (i1 < 0) i1 = 0; if (i1 > LN - 1) i1 = LN - 1;
        int i2 = sp - 2; if (i2 < 0) i2 = 0; if (i2 > LN - 1) i2 = LN - 1;
        s1code[t * NB + b] = (sp >= 1) ? tg[b][i1] : -1;
        s2code[t * NB + b] = (sp >= 2) ? tg[b][i2] : -1;
        int wk_t;
        if (shift) {
            wk_t = -1;
            if (sp >= 0 && sp < LN) tg[b][sp] = tb;
            sp = sp + 1;
            bp = bp + 1;
        } else {
            wk_t = k;
            int pos = sp - 2; if (pos < 0) pos = 0;
            if (pos < LN) tg[b][pos] = 1000 + k;
            k++;
            sp = sp - 1; if (sp < 0) sp = 0;
        }
        wkA[t * NB + b] = wk_t;
        unsigned long long m = __ballot(wk_t >= 0);
        if (b == 0) anyred[t] = (m != 0ull) ? 1 : 0;
    }
    int fi = sp - 1; if (fi < 0) fi = 0; if (fi > LN - 1) fi = LN - 1;
    fcode[b] = tg[b][fi];
}

// ---- P1 pack: per-thread slices WAp[slice8192][56] bf16 --------------------
// slice = (cg*16 + ks)*32 + c ; packed col p = cg*32+c = j*4+gate ; k = ks*56+pos
__global__ __launch_bounds__(256) void k_pack_a(
    const float* __restrict__ Wb, const float* __restrict__ W1,
    const float* __restrict__ W2, const float* __restrict__ Wl,
    const float* __restrict__ blv,
    unsigned short* __restrict__ WAp, float* __restrict__ blA) {
    int idx = blockIdx.x * 256 + threadIdx.x;
    if (idx < 8192 * 56) {
        int sl = idx / 56, pos = idx % 56;
        int c = sl & 31, ks = (sl >> 5) & 15, cg = sl >> 9;
        int p = cg * 32 + c;
        int j = p >> 2, gate = p & 3;
        int sc = gate * 128 + j;
        int k = ks * 56 + pos;
        float v;
        if (k < 256)      v = Wb[(size_t)k * GA + sc];
        else if (k < 512) v = W1[(size_t)(k - 256) * GA + sc];
        else if (k < 768) v = W2[(size_t)(k - 512) * GA + sc];
        else              v = Wl[(size_t)(k - 768) * GA + sc];
        WAp[idx] = f2bf(v);
    }
    if (idx < 512) {
        int j = idx >> 2, q = idx & 3;
        blA[idx] = blv[q * 128 + j];
    }
}

// ---- P2 pack: per-thread slices WBp[slice8192][100] bf16 -------------------
// slice = (jsl*16 + jj)*32 + ks ; col = g*256 + jsl*16 + jj
// pos<80: s-part, pos=(g*8+i2)*2+h, k=ks*16+2*i2+h ; pos>=80: WT, k=512+ks*4+2*i2+h
__global__ __launch_bounds__(256) void k_pack_b(
    const float* __restrict__ WLm, const float* __restrict__ WRm,
    const float* __restrict__ WTm, unsigned short* __restrict__ WBp) {
    int idx = blockIdx.x * 256 + threadIdx.x;
    if (idx >= 8192 * 100) return;
    int sl = idx / 100, pos = idx % 100;
    int ks = sl & 31, jj = (sl >> 5) & 15, jsl = sl >> 9;
    int g, k;
    if (pos < 80) {
        g = pos >> 4;
        int rem = pos & 15;
        k = ks * 16 + rem;
    } else {
        int p2 = pos - 80;
        g = p2 >> 2;
        int rem = p2 & 3;
        k = 512 + ks * 4 + rem;
    }
    int sc = g * 256 + jsl * 16 + jj;
    float v;
    if (k < 256)      v = WLm[(size_t)k * GR + sc];
    else if (k < 512) v = WRm[(size_t)(k - 256) * GR + sc];
    else              v = WTm[(size_t)(k - 512) * GR + sc];
    WBp[idx] = f2bf(v);
}

// ---------------- persistent role-split kernel ------------------------------
// WGs 0..127: P1 (bg = wg&7, cg = wg>>3). WGs 128..255: P2 (bg = wg&7, jsl = (wg>>3)&15)
// All WGs of batch-group bg land on XCD bg (wg%8 round-robin heuristic).
__global__ __launch_bounds__(NT, 1) void k_spinn(
    const float* __restrict__ bufh, const float* __restrict__ bufc,
    const unsigned short* __restrict__ WAp, const float* __restrict__ blA,
    const unsigned short* __restrict__ WBp, const float* __restrict__ bLv,
    const int* __restrict__ tbcode, const int* __restrict__ s1code,
    const int* __restrict__ s2code, const int* __restrict__ wkA,
    const int* __restrict__ fcode, const int* __restrict__ anyred,
    float* __restrict__ th, float* __restrict__ tc,
    float* __restrict__ redh, float* __restrict__ redc,
    unsigned* __restrict__ arrA, unsigned* __restrict__ arrC,
    float* __restrict__ out) {
    const int wg = blockIdx.x;
    const int tid = threadIdx.x;
    const int bg = wg & 7;
    const int grp = (wg >> 3) & 15;

    __shared__ union {
        struct {
            float xs[8][900];        // 8 batches x 896 (pad 900)
            float part1[16][32][9];  // ks x col x batch (pad 9: conflict-free)
            float gsum[32][9];
        } p1;
        struct {
            float xs2[8][516];       // s-part input (pad 516)
            float part2[512][41];    // (ks*16+jj) x (g*8+b) pad 41
            float xst[8][132];       // th2 (pad 132)
            float gsum2[16][41];
        } p2;
    } sm;

    unsigned rc = 0;

    if (wg < 128) {
        // =================== P1 role: gates GEMM + tracker LSTM ===================
        const int c = tid & 31, ks = tid >> 5;
        unsigned wr[28];
        {
            const unsigned* wap = (const unsigned*)WAp + (size_t)((grp * 16 + ks) * 32 + c) * 28;
            #pragma unroll
            for (int i = 0; i < 28; ++i) wr[i] = wap[i];
        }
        for (int t = 0; t < TN; ++t) {
            const int par = t & 1;
            if (t > 0) {
                if (tid < 16) {
                    while (cohLdU(&arrA[(bg * 16 + tid) * 16]) < (unsigned)t)
                        __builtin_amdgcn_s_sleep(1);
                } else if (tid < 32) {
                    while (cohLdU(&arrC[(bg * 16 + (tid - 16)) * 16]) < rc)
                        __builtin_amdgcn_s_sleep(1);
                }
                asm volatile("" ::: "memory");
                __syncthreads();
            }
            // stage xs[8][896]
            for (int g = tid; g < 1792; g += NT) {
                int row = g / 224;
                int k0 = (g - row * 224) * 4;
                int b = bg * 8 + row;
                float4 v = {0.f, 0.f, 0.f, 0.f};
                if (k0 < 256) {
                    int cc = tbcode[t * NB + b];
                    if (cc >= 0) v = *(const float4*)&bufh[((size_t)b * LN + cc) * DN + k0];
                } else if (k0 < 512) {
                    int cc = s1code[t * NB + b];
                    int kk = k0 - 256;
                    if (cc >= 1000) {
                        const float* p = &redh[((size_t)(cc - 1000) * NB + b) * DN + kk];
                        v.x = cohLd(p); v.y = cohLd(p + 1); v.z = cohLd(p + 2); v.w = cohLd(p + 3);
                    } else if (cc >= 0) v = *(const float4*)&bufh[((size_t)b * LN + cc) * DN + kk];
                } else if (k0 < 768) {
                    int cc = s2code[t * NB + b];
                    int kk = k0 - 512;
                    if (cc >= 1000) {
                        const float* p = &redh[((size_t)(cc - 1000) * NB + b) * DN + kk];
                        v.x = cohLd(p); v.y = cohLd(p + 1); v.z = cohLd(p + 2); v.w = cohLd(p + 3);
                    } else if (cc >= 0) v = *(const float4*)&bufh[((size_t)b * LN + cc) * DN + kk];
                } else {
                    const float* p = &th[((size_t)par * NB + b) * TKN + (k0 - 768)];
                    v.x = cohLd(p); v.y = cohLd(p + 1); v.z = cohLd(p + 2); v.w = cohLd(p + 3);
                }
                *(float4*)&sm.p1.xs[row][k0] = v;
            }
            __syncthreads();
            // GEMM from register weights
            {
                float acc[8];
                #pragma unroll
                for (int b = 0; b < 8; ++b) acc[b] = 0.f;
                #pragma unroll
                for (int i2 = 0; i2 < 28; ++i2) {
                    unsigned wv = wr[i2];
                    float wf0 = bf2f(wv & 0xFFFF), wf1 = bf2f(wv >> 16);
                    int k = ks * 56 + 2 * i2;
                    #pragma unroll
                    for (int b = 0; b < 8; ++b) {
                        float2 x = *(const float2*)&sm.p1.xs[b][k];
                        acc[b] += x.x * wf0 + x.y * wf1;
                    }
                }
                #pragma unroll
                for (int b = 0; b < 8; ++b) sm.p1.part1[ks][c][b] = acc[b];
            }
            __syncthreads();
            if (tid < 256) {
                int col = tid >> 3, b = tid & 7;
                float s = 0.f;
                #pragma unroll
                for (int k2 = 0; k2 < 16; ++k2) s += sm.p1.part1[k2][col][b];
                if (t > 0) s += blA[grp * 32 + col];
                sm.p1.gsum[col][b] = s;
            }
            __syncthreads();
            if (tid < 64) {
                int jloc = tid >> 3, b = tid & 7;
                int bb = bg * 8 + b;
                int j = grp * 8 + jloc;
                float a  = sm.p1.gsum[jloc * 4 + 0][b];
                float i_ = sm.p1.gsum[jloc * 4 + 1][b];
                float f  = sm.p1.gsum[jloc * 4 + 2][b];
                float o  = sm.p1.gsum[jloc * 4 + 3][b];
                float tco = tc[((size_t)par * NB + bb) * TKN + j];
                float c2v = tanhf(a) * sigf(i_) + sigf(f) * tco;
                float h2 = sigf(o) * tanhf(c2v);
                tc[((size_t)(par ^ 1) * NB + bb) * TKN + j] = c2v;
                cohSt(&th[((size_t)(par ^ 1) * NB + bb) * TKN + j], h2);
            }
            __syncthreads();   // drains vmcnt: th2 stores at coherence point
            if (tid == 0) cohStU(&arrA[(bg * 16 + grp) * 16], (unsigned)(t + 1));
            rc += (anyred[t] != 0) ? 1u : 0u;
        }
    } else {
        // =================== P2 role: rgates GEMM + TreeLSTM ===================
        const int jj = tid & 15, ks = tid >> 4;
        unsigned ws[40], wt2[10];
        {
            const unsigned* wbp = (const unsigned*)WBp + (size_t)((grp * 16 + jj) * 32 + ks) * 50;
            #pragma unroll
            for (int i = 0; i < 40; ++i) ws[i] = wbp[i];
            #pragma unroll
            for (int i = 0; i < 10; ++i) wt2[i] = wbp[40 + i];
        }
        for (int t = 0; t < TN; ++t) {
            if (!anyred[t]) continue;
            const int par2 = (t & 1) ^ 1;
            // wait: all prior reduces of this bg visible
            if (tid < 16) {
                while (cohLdU(&arrC[(bg * 16 + tid) * 16]) < rc)
                    __builtin_amdgcn_s_sleep(1);
            }
            asm volatile("" ::: "memory");
            __syncthreads();
            // stage s-part xs2[8][512]
            for (int g = tid; g < 1024; g += NT) {
                int row = g >> 7;
                int k0 = (g & 127) * 4;
                int b = bg * 8 + row;
                float4 v = {0.f, 0.f, 0.f, 0.f};
                if (k0 < 256) {
                    int cc = s2code[t * NB + b];
                    if (cc >= 1000) {
                        const float* p = &redh[((size_t)(cc - 1000) * NB + b) * DN + k0];
                        v.x = cohLd(p); v.y = cohLd(p + 1); v.z = cohLd(p + 2); v.w = cohLd(p + 3);
                    } else if (cc >= 0) v = *(const float4*)&bufh[((size_t)b * LN + cc) * DN + k0];
                } else {
                    int cc = s1code[t * NB + b];
                    int kk = k0 - 256;
                    if (cc >= 1000) {
                        const float* p = &redh[((size_t)(cc - 1000) * NB + b) * DN + kk];
                        v.x = cohLd(p); v.y = cohLd(p + 1); v.z = cohLd(p + 2); v.w = cohLd(p + 3);
                    } else if (cc >= 0) v = *(const float4*)&bufh[((size_t)b * LN + cc) * DN + kk];
                }
                *(float4*)&sm.p2.xs2[row][k0] = v;
            }
            __syncthreads();
            // s-part GEMM (K=512) from register weights
            float acc[5][8];
            #pragma unroll
            for (int g = 0; g < 5; ++g)
                #pragma unroll
                for (int b = 0; b < 8; ++b) acc[g][b] = 0.f;
            #pragma unroll
            for (int i2 = 0; i2 < 8; ++i2) {
                int k = ks * 16 + 2 * i2;
                float2 x[8];
                #pragma unroll
                for (int b = 0; b < 8; ++b) x[b] = *(const float2*)&sm.p2.xs2[b][k];
                #pragma unroll
                for (int g = 0; g < 5; ++g) {
                    unsigned wv = ws[g * 8 + i2];
                    float wf0 = bf2f(wv & 0xFFFF), wf1 = bf2f(wv >> 16);
                    #pragma unroll
                    for (int b = 0; b < 8; ++b)
                        acc[g][b] += x[b].x * wf0 + x[b].y * wf1;
                }
            }
            // wait th2(t)
            if (tid < 16) {
                while (cohLdU(&arrA[(bg * 16 + tid) * 16]) < (unsigned)(t + 1))
                    __builtin_amdgcn_s_sleep(1);
            }
            asm volatile("" ::: "memory");
            __syncthreads();
            if (tid < 256) {
                int row = tid >> 5;
                int k0 = (tid & 31) * 4;
                int b = bg * 8 + row;
                const float* p = &th[((size_t)par2 * NB + b) * TKN + k0];
                float4 v;
                v.x = cohLd(p); v.y = cohLd(p + 1); v.z = cohLd(p + 2); v.w = cohLd(p + 3);
                *(float4*)&sm.p2.xst[row][k0] = v;
            }
            __syncthreads();
            // WT part (K=128)
            #pragma unroll
            for (int i2 = 0; i2 < 2; ++i2) {
                int k = ks * 4 + 2 * i2;
                float2 x[8];
                #pragma unroll
                for (int b = 0; b < 8; ++b) x[b] = *(const float2*)&sm.p2.xst[b][k];
                #pragma unroll
                for (int g = 0; g < 5; ++g) {
                    unsigned wv = wt2[g * 2 + i2];
                    float wf0 = bf2f(wv & 0xFFFF), wf1 = bf2f(wv >> 16);
                    #pragma unroll
                    for (int b = 0; b < 8; ++b)
                        acc[g][b] += x[b].x * wf0 + x[b].y * wf1;
                }
            }
            #pragma unroll
            for (int g = 0; g < 5; ++g)
                #pragma unroll
                for (int b = 0; b < 8; ++b)
                    sm.p2.part2[ks * 16 + jj][g * 8 + b] = acc[g][b];
            __syncthreads();
            // reduce over 32 kslices
            for (int o = tid; o < 640; o += NT) {
                int jj2 = o / 40, r = o - jj2 * 40;
                float s = 0.f;
                #pragma unroll
                for (int k2 = 0; k2 < 32; ++k2) s += sm.p2.part2[k2 * 16 + jj2][r];
                sm.p2.gsum2[jj2][r] = s;
            }
            __syncthreads();
            // TreeLSTM
            if (tid < 128) {
                int jj2 = tid >> 3, b = tid & 7;
                int bb = bg * 8 + b;
                int wk = wkA[t * NB + bb];
                if (wk >= 0) {
                    int j = grp * 16 + jj2;
                    float ga  = sm.p2.gsum2[jj2][0 * 8 + b] + bLv[0 * 256 + j];
                    float gi  = sm.p2.gsum2[jj2][1 * 8 + b] + bLv[1 * 256 + j];
                    float gf1 = sm.p2.gsum2[jj2][2 * 8 + b] + bLv[2 * 256 + j];
                    float gf2 = sm.p2.gsum2[jj2][3 * 8 + b] + bLv[3 * 256 + j];
                    float go  = sm.p2.gsum2[jj2][4 * 8 + b] + bLv[4 * 256 + j];
                    int c1 = s1code[t * NB + bb], c2 = s2code[t * NB + bb];
                    float s2cv = (c2 == -1) ? 0.f
                                : ((c2 >= 1000) ? redc[((size_t)(c2 - 1000) * NB + bb) * DN + j]
                                                : bufc[((size_t)bb * LN + c2) * DN + j]);
                    float s1cv = (c1 == -1) ? 0.f
                                : ((c1 >= 1000) ? redc[((size_t)(c1 - 1000) * NB + bb) * DN + j]
                                                : bufc[((size_t)bb * LN + c1) * DN + j]);
                    float cc = tanhf(ga) * sigf(gi) + sigf(gf1) * s2cv + sigf(gf2) * s1cv;
                    float hh = sigf(go) * tanhf(cc);
                    cohSt(&redh[((size_t)wk * NB + bb) * DN + j], hh);   // cross-WG
                    redc[((size_t)wk * NB + bb) * DN + j] = cc;          // owner-stable
                }
            }
            __syncthreads();   // drains vmcnt: redh stores at coherence point
            if (tid == 0) cohStU(&arrC[(bg * 16 + grp) * 16], rc + 1u);
            rc += 1u;
        }
        // final output: this WG owns (bg, jsl) slice of out
        if (tid < 128) {
            int jj2 = tid >> 3, b = tid & 7;
            int bb = bg * 8 + b;
            int j = grp * 16 + jj2;
            int c = fcode[bb];
            float h = 0.f, cv = 0.f;
            if (c >= 1000) {
                h  = cohLd(&redh[((size_t)(c - 1000) * NB + bb) * DN + j]);
                cv = redc[((size_t)(c - 1000) * NB + bb) * DN + j];
            } else if (c >= 0) {
                h  = bufh[((size_t)bb * LN + c) * DN + j];
                cv = bufc[((size_t)bb * LN + c) * DN + j];
            }
            out[(size_t)bb * 2 * DN + j]      = h;
            out[(size_t)bb * 2 * DN + DN + j] = cv;
        }
    }
}

extern "C" void kernel_launch(void* const* d_in, const int* in_sizes, int n_in,
                              void* d_out, int out_size, void* d_ws, size_t ws_size,
                              hipStream_t stream) {
    const float* bufh = (const float*)d_in[0];
    const float* bufc = (const float*)d_in[1];
    const float* Wb   = (const float*)d_in[2];
    const float* W1   = (const float*)d_in[3];
    const float* W2   = (const float*)d_in[4];
    const float* Wl   = (const float*)d_in[5];
    const float* blv  = (const float*)d_in[6];
    const float* WLm  = (const float*)d_in[7];
    const float* bLv  = (const float*)d_in[8];
    const float* WR   = (const float*)d_in[9];
    const float* WT   = (const float*)d_in[10];
    const int* trans  = (const int*)d_in[11];
    float* out = (float*)d_out;

    char* p = (char*)d_ws;
    auto carve = [&](size_t bytes) -> char* {
        char* r = p;
        p += (bytes + 255) & ~(size_t)255;
        return r;
    };
    int* tbcode = (int*)carve((size_t)TN * NB * 4);
    int* s1code = (int*)carve((size_t)TN * NB * 4);
    int* s2code = (int*)carve((size_t)TN * NB * 4);
    int* wkA    = (int*)carve((size_t)TN * NB * 4);
    int* fcode  = (int*)carve((size_t)NB * 4);
    int* anyred = (int*)carve((size_t)TN * 4);
    float* th   = (float*)carve((size_t)2 * NB * TKN * 4);
    float* tc   = (float*)carve((size_t)2 * NB * TKN * 4);
    float* redh = (float*)carve((size_t)RMAX * NB * DN * 4);
    float* redc = (float*)carve((size_t)RMAX * NB * DN * 4);
    unsigned short* WAp = (unsigned short*)carve((size_t)8192 * 56 * 2);
    float* blA  = (float*)carve((size_t)512 * 4);
    unsigned short* WBp = (unsigned short*)carve((size_t)8192 * 100 * 2);
    unsigned* arrA = (unsigned*)carve((size_t)128 * 16 * 4);
    unsigned* arrC = (unsigned*)carve((size_t)128 * 16 * 4);

    hipMemsetAsync(th, 0, (size_t)2 * NB * TKN * 4, stream);
    hipMemsetAsync(tc, 0, (size_t)2 * NB * TKN * 4, stream);
    hipMemsetAsync(arrA, 0, (size_t)128 * 16 * 4, stream);
    hipMemsetAsync(arrC, 0, (size_t)128 * 16 * 4, stream);

    k_sched<<<1, 64, 0, stream>>>(trans, tbcode, s1code, s2code, wkA, fcode, anyred);
    k_pack_a<<<(8192 * 56 + 255) / 256, 256, 0, stream>>>(Wb, W1, W2, Wl, blv, WAp, blA);
    k_pack_b<<<(8192 * 100 + 255) / 256, 256, 0, stream>>>(WLm, WR, WT, WBp);
    k_spinn<<<NWG, NT, 0, stream>>>(bufh, bufc, WAp, blA, WBp, bLv,
                                    tbcode, s1code, s2code, wkA, fcode, anyred,
                                    th, tc, redh, redc, arrA, arrC, out);
}

// Round 12
// 889.542 us; speedup vs baseline: 1.3490x; 1.3490x over previous
//
#include <hip/hip_runtime.h>
#include <cstdint>
#include <cstddef>

#define NB 64      // batch
#define LN 48      // buffer length
#define DN 256     // hidden dim
#define TKN 128    // tracker dim
#define TN 95      // steps
#define RMAX 48    // max reduces per batch
#define GA 512     // 4*TK
#define GR 1280    // 5*D
#define NWG 256
#define NT 512

__device__ __forceinline__ float sigf(float x) { return 1.0f / (1.0f + expf(-x)); }

__device__ __forceinline__ float bf2f(unsigned u16) {
    unsigned x = u16 << 16;
    return __builtin_bit_cast(float, x);
}
__device__ __forceinline__ unsigned short f2bf(float f) {
    unsigned x = __builtin_bit_cast(unsigned, f);
    unsigned r = (x + 0x7FFFu + ((x >> 16) & 1u)) >> 16;
    return (unsigned short)r;
}

// coherent (sc1) access — bypasses non-coherent per-XCD L2 (verified r4-r10)
__device__ __forceinline__ float cohLd(const float* p) {
    return __hip_atomic_load(p, __ATOMIC_RELAXED, __HIP_MEMORY_SCOPE_AGENT);
}
__device__ __forceinline__ void cohSt(float* p, float v) {
    __hip_atomic_store(p, v, __ATOMIC_RELAXED, __HIP_MEMORY_SCOPE_AGENT);
}
__device__ __forceinline__ unsigned cohLdU(const unsigned* p) {
    return __hip_atomic_load(p, __ATOMIC_RELAXED, __HIP_MEMORY_SCOPE_AGENT);
}
__device__ __forceinline__ void cohStU(unsigned* p, unsigned v) {
    __hip_atomic_store(p, v, __ATOMIC_RELAXED, __HIP_MEMORY_SCOPE_AGENT);
}

// direct all-observe grid barrier: each WG stores its slot; threads 0..255 of
// EVERY WG poll all 256 slots (one L3 RTT after last arrival; no watcher hop).
// __syncthreads() drains vmcnt(0) before the arrival store (verified r4-r10).
__device__ __forceinline__ void gbarD(unsigned* slots, unsigned& gph) {
    __syncthreads();
    gph += 1;
    if (threadIdx.x == 0) cohStU(&slots[blockIdx.x * 16], gph);
    if (threadIdx.x < NWG) {
        while (cohLdU(&slots[threadIdx.x * 16]) < gph)
            __builtin_amdgcn_s_sleep(1);
    }
    asm volatile("" ::: "memory");
    __syncthreads();
}

// pair-scoped sync (shift steps): only the 8 WGs {8u..8u+7} sharing batch-pair u
// exchange th2 — sync just those; 32 pair-groups drift independently.
__device__ __forceinline__ void psync(unsigned* slotsP, int u, int xcd, unsigned& pph) {
    __syncthreads();
    pph += 1;
    if (threadIdx.x == 0) cohStU(&slotsP[(u * 8 + xcd) * 16], pph);
    if (threadIdx.x < 8) {
        while (cohLdU(&slotsP[(u * 8 + threadIdx.x) * 16]) < pph)
            __builtin_amdgcn_s_sleep(1);
    }
    asm volatile("" ::: "memory");
    __syncthreads();
}

// ---------------- schedule builder (verified r1-r10) ------------------------
__global__ void k_sched(const int* __restrict__ trans,
                        int* __restrict__ tbcode, int* __restrict__ s1code,
                        int* __restrict__ s2code, int* __restrict__ wkA,
                        int* __restrict__ fcode, int* __restrict__ anyred) {
    __shared__ int tg[NB][LN];
    int b = threadIdx.x;
    if (b >= NB) return;
    for (int i = 0; i < LN; ++i) tg[b][i] = -1;
    int sp = 0, bp = 0, k = 0;
    for (int t = 0; t < TN; ++t) {
        int tr = trans[b * TN + t];
        int shift = (tr == 0);
        int tb = (bp < LN) ? bp : -1;
        tbcode[t * NB + b] = tb;
        int i1 = sp - 1; if (i1 < 0) i1 = 0; if (i1 > LN - 1) i1 = LN - 1;
        int i2 = sp - 2; if (i2 < 0) i2 = 0; if (i2 > LN - 1) i2 = LN - 1;
        s1code[t * NB + b] = (sp >= 1) ? tg[b][i1] : -1;
        s2code[t * NB + b] = (sp >= 2) ? tg[b][i2] : -1;
        int wk_t;
        if (shift) {
            wk_t = -1;
            if (sp >= 0 && sp < LN) tg[b][sp] = tb;
            sp = sp + 1;
            bp = bp + 1;
        } else {
            wk_t = k;
            int pos = sp - 2; if (pos < 0) pos = 0;
            if (pos < LN) tg[b][pos] = 1000 + k;
            k++;
            sp = sp - 1; if (sp < 0) sp = 0;
        }
        wkA[t * NB + b] = wk_t;
        unsigned long long m = __ballot(wk_t >= 0);
        if (b == 0) anyred[t] = (m != 0ull) ? 1 : 0;
    }
    int fi = sp - 1; if (fi < 0) fi = 0; if (fi > LN - 1) fi = LN - 1;
    fcode[b] = tg[b][fi];
}

// ---- P1 pack (bf16): WAb[slice8][k896][64 cols]; packed col p = j*4+gate ----
__global__ __launch_bounds__(256) void k_pack_a(
    const float* __restrict__ Wb, const float* __restrict__ W1,
    const float* __restrict__ W2, const float* __restrict__ Wl,
    const float* __restrict__ blv,
    unsigned short* __restrict__ WAb, float* __restrict__ blA) {
    int idx = blockIdx.x * 256 + threadIdx.x;
    if (idx < 8 * 896 * 64) {
        int s = idx / (896 * 64);
        int r = idx % (896 * 64);
        int k = r >> 6, c = r & 63;
        int p = s * 64 + c;
        int j = p >> 2, q = p & 3;
        int sc = q * 128 + j;
        float v;
        if (k < 256)      v = Wb[(size_t)k * GA + sc];
        else if (k < 512) v = W1[(size_t)(k - 256) * GA + sc];
        else if (k < 768) v = W2[(size_t)(k - 512) * GA + sc];
        else              v = Wl[(size_t)(k - 768) * GA + sc];
        WAb[idx] = f2bf(v);
    }
    if (idx < 512) {
        int j = idx >> 2, q = idx & 3;
        blA[idx] = blv[q * 128 + j];
    }
}

// ---- P2 pack (bf16): WBb[slice16][k640][jj16*8slots]; slot g<5 real ---------
__global__ __launch_bounds__(256) void k_pack_b(
    const float* __restrict__ WLm, const float* __restrict__ WRm,
    const float* __restrict__ WTm, unsigned short* __restrict__ WBb) {
    int idx = blockIdx.x * 256 + threadIdx.x;
    if (idx >= 16 * 640 * 128) return;
    int s = idx / (640 * 128);
    int r = idx % (640 * 128);
    int k = r >> 7, cc = r & 127;
    int jj = cc >> 3, g = cc & 7;
    float v = 0.f;
    if (g < 5) {
        int sc = g * 256 + s * 16 + jj;
        if (k < 256)      v = WLm[(size_t)k * GR + sc];
        else if (k < 512) v = WRm[(size_t)(k - 256) * GR + sc];
        else              v = WTm[(size_t)(k - 512) * GR + sc];
    }
    WBb[idx] = f2bf(v);
}

// ---------------- persistent full-scan kernel (r10 structure) ---------------
__global__ __launch_bounds__(NT, 1) void k_spinn(
    const float* __restrict__ bufh, const float* __restrict__ bufc,
    const unsigned short* __restrict__ WAb, const float* __restrict__ blA,
    const unsigned short* __restrict__ WBb, const float* __restrict__ bLv,
    const int* __restrict__ tbcode, const int* __restrict__ s1code,
    const int* __restrict__ s2code, const int* __restrict__ wkA,
    const int* __restrict__ fcode, const int* __restrict__ anyred,
    float* __restrict__ th, float* __restrict__ tc,
    float* __restrict__ redh, float* __restrict__ redc,
    unsigned* __restrict__ slots, unsigned* __restrict__ slotsP,
    float* __restrict__ out) {
    const int wg = blockIdx.x;
    const int tid = threadIdx.x;
    const int lane = tid & 63;
    const int w = tid >> 6;                 // 8 waves
    unsigned gph = 0, pph = 0;

    const int xcd = wg & 7;
    const int u = wg >> 3;                  // 0..31
    const int jg = xcd;                     // P1 64-col slice (114KB bf16, L2/XCD)
    const int bg1 = u;                      // P1: 2 b (pair u)
    const int bg2 = u >> 1;                 // P2: 4 b
    const int jgw = (u & 1) + 2 * xcd;      // P2 slice (160KB bf16; 2/XCD)

    __shared__ float xs[2][896];            // P1 input
    __shared__ float part1[2][64][33];      // P1 partials (2-way bank max)
    __shared__ float gsum[2][64];
    __shared__ float xs2[4][512];           // P2 s-part input
    __shared__ float part2[16][16][21];     // P2 partials, padded
    __shared__ float gsum2[4][5][16];
    __shared__ float xst[4][128];           // th2 for WT part

    for (int t = 0; t < TN; ++t) {
        const int par = t & 1;
        const bool red = anyred[t] != 0;

        // ============ stage: P1 xs (448 f4) + P2s xs2 (512 f4) ============
        int ngroups = red ? 960 : 448;
        for (int g = tid; g < ngroups; g += NT) {
            if (g < 448) {
                int row = g & 1, k0 = (g >> 1) * 4;
                int b = bg1 * 2 + row;
                float4 v = {0.f, 0.f, 0.f, 0.f};
                if (k0 < 256) {
                    int c = tbcode[t * NB + b];
                    if (c >= 0) v = *(const float4*)&bufh[((size_t)b * LN + c) * DN + k0];
                } else if (k0 < 512) {
                    int c = s1code[t * NB + b];
                    int kk = k0 - 256;
                    if (c >= 1000) {
                        const float* p = &redh[((size_t)(c - 1000) * NB + b) * DN + kk];
                        v.x = cohLd(p); v.y = cohLd(p + 1); v.z = cohLd(p + 2); v.w = cohLd(p + 3);
                    } else if (c >= 0) v = *(const float4*)&bufh[((size_t)b * LN + c) * DN + kk];
                } else if (k0 < 768) {
                    int c = s2code[t * NB + b];
                    int kk = k0 - 512;
                    if (c >= 1000) {
                        const float* p = &redh[((size_t)(c - 1000) * NB + b) * DN + kk];
                        v.x = cohLd(p); v.y = cohLd(p + 1); v.z = cohLd(p + 2); v.w = cohLd(p + 3);
                    } else if (c >= 0) v = *(const float4*)&bufh[((size_t)b * LN + c) * DN + kk];
                } else {
                    const float* p = &th[((size_t)par * NB + b) * TKN + (k0 - 768)];
                    v.x = cohLd(p); v.y = cohLd(p + 1); v.z = cohLd(p + 2); v.w = cohLd(p + 3);
                }
                *(float4*)&xs[row][k0] = v;
            } else {
                int g2 = g - 448;
                int row = g2 & 3, k0 = (g2 >> 2) * 4;
                int b = bg2 * 4 + row;
                float4 v = {0.f, 0.f, 0.f, 0.f};
                if (k0 < 256) {
                    int c = s2code[t * NB + b];
                    if (c >= 1000) {
                        const float* p = &redh[((size_t)(c - 1000) * NB + b) * DN + k0];
                        v.x = cohLd(p); v.y = cohLd(p + 1); v.z = cohLd(p + 2); v.w = cohLd(p + 3);
                    } else if (c >= 0) v = *(const float4*)&bufh[((size_t)b * LN + c) * DN + k0];
                } else {
                    int c = s1code[t * NB + b];
                    int kk = k0 - 256;
                    if (c >= 1000) {
                        const float* p = &redh[((size_t)(c - 1000) * NB + b) * DN + kk];
                        v.x = cohLd(p); v.y = cohLd(p + 1); v.z = cohLd(p + 2); v.w = cohLd(p + 3);
                    } else if (c >= 0) v = *(const float4*)&bufh[((size_t)b * LN + c) * DN + kk];
                }
                *(float4*)&xs2[row][k0] = v;
            }
        }
        __syncthreads();

        // ============ concurrent GEMMs: waves 0-3 P1, waves 4-7 P2s ============
        float acc[5][4];   // P2 accumulators live across barrier A in registers
        if (w < 4) {
            int c8 = lane & 7, kq = lane >> 3;
            int kbase = w * 224;
            const uint4* wp = (const uint4*)WAb + ((size_t)(jg * 896 + kbase + kq) * 8) + c8;
            float a0[8], a1[8];
            #pragma unroll
            for (int cc = 0; cc < 8; ++cc) { a0[cc] = 0.f; a1[cc] = 0.f; }
            #pragma unroll 4
            for (int i = 0; i < 28; ++i) {
                uint4 wv = wp[(size_t)i * 64];          // wave: 1KB contiguous
                int k = kbase + kq + i * 8;
                float x0 = xs[0][k], x1 = xs[1][k];
                float wf0 = bf2f(wv.x & 0xFFFF), wf1 = bf2f(wv.x >> 16);
                float wf2 = bf2f(wv.y & 0xFFFF), wf3 = bf2f(wv.y >> 16);
                float wf4 = bf2f(wv.z & 0xFFFF), wf5 = bf2f(wv.z >> 16);
                float wf6 = bf2f(wv.w & 0xFFFF), wf7 = bf2f(wv.w >> 16);
                a0[0] += x0 * wf0; a1[0] += x1 * wf0;
                a0[1] += x0 * wf1; a1[1] += x1 * wf1;
                a0[2] += x0 * wf2; a1[2] += x1 * wf2;
                a0[3] += x0 * wf3; a1[3] += x1 * wf3;
                a0[4] += x0 * wf4; a1[4] += x1 * wf4;
                a0[5] += x0 * wf5; a1[5] += x1 * wf5;
                a0[6] += x0 * wf6; a1[6] += x1 * wf6;
                a0[7] += x0 * wf7; a1[7] += x1 * wf7;
            }
            int ks = w * 8 + kq;
            #pragma unroll
            for (int cc = 0; cc < 8; ++cc) {
                part1[0][c8 * 8 + cc][ks] = a0[cc];
                part1[1][c8 * 8 + cc][ks] = a1[cc];
            }
        } else if (red) {
            int t2 = tid - 256, jj = t2 & 15, ks = t2 >> 4;   // 16 j x 16 kslices
            #pragma unroll
            for (int g = 0; g < 5; ++g)
                #pragma unroll
                for (int b4 = 0; b4 < 4; ++b4) acc[g][b4] = 0.f;
            const uint4* wb = (const uint4*)WBb + ((size_t)(jgw * 640 + ks * 32) * 16) + jj;
            #pragma unroll 4
            for (int i = 0; i < 32; ++i) {
                uint4 wv = wb[(size_t)i * 16];          // 8 slots (5 real) = 16B
                float w0 = bf2f(wv.x & 0xFFFF), w1 = bf2f(wv.x >> 16);
                float w2 = bf2f(wv.y & 0xFFFF), w3 = bf2f(wv.y >> 16);
                float w4 = bf2f(wv.z & 0xFFFF);
                int k = ks * 32 + i;
                float x0 = xs2[0][k], x1 = xs2[1][k], x2 = xs2[2][k], x3 = xs2[3][k];
                acc[0][0] += x0 * w0; acc[1][0] += x0 * w1; acc[2][0] += x0 * w2; acc[3][0] += x0 * w3; acc[4][0] += x0 * w4;
                acc[0][1] += x1 * w0; acc[1][1] += x1 * w1; acc[2][1] += x1 * w2; acc[3][1] += x1 * w3; acc[4][1] += x1 * w4;
                acc[0][2] += x2 * w0; acc[1][2] += x2 * w1; acc[2][2] += x2 * w2; acc[3][2] += x2 * w3; acc[4][2] += x2 * w4;
                acc[0][3] += x3 * w0; acc[1][3] += x3 * w1; acc[2][3] += x3 * w2; acc[3][3] += x3 * w3; acc[4][3] += x3 * w4;
            }
        }
        __syncthreads();

        // ============ P1 reduce + tracker LSTM ============
        if (tid < 128) {
            int b = tid & 1, col = tid >> 1;
            float s = 0.f;
            #pragma unroll
            for (int ks = 0; ks < 32; ++ks) s += part1[b][col][ks];
            if (t > 0) s += blA[jg * 64 + col];
            gsum[b][col] = s;
        }
        __syncthreads();
        if (tid < 32) {
            int bl_ = tid >> 4, jj = tid & 15;
            int b = bg1 * 2 + bl_;
            int j = jg * 16 + jj;
            float4 g4 = *(const float4*)&gsum[bl_][jj * 4];     // a,i,f,o
            float tco = tc[((size_t)par * NB + b) * TKN + j];
            float c2v = tanhf(g4.x) * sigf(g4.y) + sigf(g4.z) * tco;
            float h2 = sigf(g4.w) * tanhf(c2v);
            tc[((size_t)(par ^ 1) * NB + b) * TKN + j] = c2v;
            cohSt(&th[((size_t)(par ^ 1) * NB + b) * TKN + j], h2);
        }

        if (!red) {
            // shift step: only the 8 WGs of pair u exchange th2 — pair sync
            psync(slotsP, u, xcd, pph);
            continue;
        }
        gbarD(slots, gph);   // barrier A: th2 visible grid-wide

        // ============ WT part (K=128) + reduce + TreeLSTM ============
        {
            int b4 = tid >> 7, kk = tid & 127;
            xst[b4][kk] = cohLd(&th[((size_t)(par ^ 1) * NB + bg2 * 4 + b4) * TKN + kk]);
        }
        __syncthreads();
        if (w >= 4) {
            int t2 = tid - 256, jj = t2 & 15, ks = t2 >> 4;
            const uint4* wb = (const uint4*)WBb + ((size_t)(jgw * 640 + 512 + ks * 8) * 16) + jj;
            #pragma unroll
            for (int i = 0; i < 8; ++i) {
                uint4 wv = wb[(size_t)i * 16];
                float w0 = bf2f(wv.x & 0xFFFF), w1 = bf2f(wv.x >> 16);
                float w2 = bf2f(wv.y & 0xFFFF), w3 = bf2f(wv.y >> 16);
                float w4 = bf2f(wv.z & 0xFFFF);
                int kk2 = ks * 8 + i;
                float x0 = xst[0][kk2], x1 = xst[1][kk2], x2 = xst[2][kk2], x3 = xst[3][kk2];
                acc[0][0] += x0 * w0; acc[1][0] += x0 * w1; acc[2][0] += x0 * w2; acc[3][0] += x0 * w3; acc[4][0] += x0 * w4;
                acc[0][1] += x1 * w0; acc[1][1] += x1 * w1; acc[2][1] += x1 * w2; acc[3][1] += x1 * w3; acc[4][1] += x1 * w4;
                acc[0][2] += x2 * w0; acc[1][2] += x2 * w1; acc[2][2] += x2 * w2; acc[3][2] += x2 * w3; acc[4][2] += x2 * w4;
                acc[0][3] += x3 * w0; acc[1][3] += x3 * w1; acc[2][3] += x3 * w2; acc[3][3] += x3 * w3; acc[4][3] += x3 * w4;
            }
            #pragma unroll
            for (int g = 0; g < 5; ++g)
                #pragma unroll
                for (int b4 = 0; b4 < 4; ++b4)
                    part2[ks][jj][g * 4 + b4] = acc[g][b4];
        }
        __syncthreads();
        if (tid < 320) {
            int g = tid >> 6, r = tid & 63;
            int bl_ = r >> 4, jj = r & 15;
            float s = 0.f;
            #pragma unroll
            for (int ks = 0; ks < 16; ++ks) s += part2[ks][jj][g * 4 + bl_];
            gsum2[bl_][g][jj] = s;
        }
        __syncthreads();
        if (tid < 64) {
            int bl_ = tid >> 4, jj = tid & 15;
            int b = bg2 * 4 + bl_;
            int wk = wkA[t * NB + b];
            if (wk >= 0) {
                int j = jgw * 16 + jj;
                float ga  = gsum2[bl_][0][jj] + bLv[0 * 256 + j];
                float gi  = gsum2[bl_][1][jj] + bLv[1 * 256 + j];
                float gf1 = gsum2[bl_][2][jj] + bLv[2 * 256 + j];
                float gf2 = gsum2[bl_][3][jj] + bLv[3 * 256 + j];
                float go  = gsum2[bl_][4][jj] + bLv[4 * 256 + j];
                int c1 = s1code[t * NB + b], c2 = s2code[t * NB + b];
                float s2cv = (c2 == -1) ? 0.f
                            : ((c2 >= 1000) ? redc[((size_t)(c2 - 1000) * NB + b) * DN + j]
                                            : bufc[((size_t)b * LN + c2) * DN + j]);
                float s1cv = (c1 == -1) ? 0.f
                            : ((c1 >= 1000) ? redc[((size_t)(c1 - 1000) * NB + b) * DN + j]
                                            : bufc[((size_t)b * LN + c1) * DN + j]);
                float cc = tanhf(ga) * sigf(gi) + sigf(gf1) * s2cv + sigf(gf2) * s1cv;
                float hh = sigf(go) * tanhf(cc);
                cohSt(&redh[((size_t)wk * NB + b) * DN + j], hh);   // cross-WG
                redc[((size_t)wk * NB + b) * DN + j] = cc;          // owner-stable
            }
        }
        gbarD(slots, gph);   // barrier C: redh visible grid-wide
    }

    // ===== final output: P2-owner (b,j) writes its slice =====
    if (tid < 64) {
        int bl_ = tid >> 4, jj = tid & 15;
        int b = bg2 * 4 + bl_;
        int j = jgw * 16 + jj;
        int c = fcode[b];
        float h = 0.f, cv = 0.f;
        if (c >= 1000) {
            h  = cohLd(&redh[((size_t)(c - 1000) * NB + b) * DN + j]);
            cv = redc[((size_t)(c - 1000) * NB + b) * DN + j];
        } else if (c >= 0) {
            h  = bufh[((size_t)b * LN + c) * DN + j];
            cv = bufc[((size_t)b * LN + c) * DN + j];
        }
        out[(size_t)b * 2 * DN + j]      = h;
        out[(size_t)b * 2 * DN + DN + j] = cv;
    }
}

extern "C" void kernel_launch(void* const* d_in, const int* in_sizes, int n_in,
                              void* d_out, int out_size, void* d_ws, size_t ws_size,
                              hipStream_t stream) {
    const float* bufh = (const float*)d_in[0];
    const float* bufc = (const float*)d_in[1];
    const float* Wb   = (const float*)d_in[2];
    const float* W1   = (const float*)d_in[3];
    const float* W2   = (const float*)d_in[4];
    const float* Wl   = (const float*)d_in[5];
    const float* blv  = (const float*)d_in[6];
    const float* WLm  = (const float*)d_in[7];
    const float* bLv  = (const float*)d_in[8];
    const float* WR   = (const float*)d_in[9];
    const float* WT   = (const float*)d_in[10];
    const int* trans  = (const int*)d_in[11];
    float* out = (float*)d_out;

    char* p = (char*)d_ws;
    auto carve = [&](size_t bytes) -> char* {
        char* r = p;
        p += (bytes + 255) & ~(size_t)255;
        return r;
    };
    int* tbcode = (int*)carve((size_t)TN * NB * 4);
    int* s1code = (int*)carve((size_t)TN * NB * 4);
    int* s2code = (int*)carve((size_t)TN * NB * 4);
    int* wkA    = (int*)carve((size_t)TN * NB * 4);
    int* fcode  = (int*)carve((size_t)NB * 4);
    int* anyred = (int*)carve((size_t)TN * 4);
    float* th   = (float*)carve((size_t)2 * NB * TKN * 4);
    float* tc   = (float*)carve((size_t)2 * NB * TKN * 4);
    float* redh = (float*)carve((size_t)RMAX * NB * DN * 4);
    float* redc = (float*)carve((size_t)RMAX * NB * DN * 4);
    unsigned short* WAb = (unsigned short*)carve((size_t)8 * 896 * 64 * 2);
    float* blA  = (float*)carve((size_t)512 * 4);
    unsigned short* WBb = (unsigned short*)carve((size_t)16 * 640 * 128 * 2);
    unsigned* slots  = (unsigned*)carve((size_t)NWG * 16 * 4);
    unsigned* slotsP = (unsigned*)carve((size_t)NWG * 16 * 4);

    hipMemsetAsync(th, 0, (size_t)2 * NB * TKN * 4, stream);
    hipMemsetAsync(tc, 0, (size_t)2 * NB * TKN * 4, stream);
    hipMemsetAsync(slots, 0, (size_t)NWG * 16 * 4, stream);
    hipMemsetAsync(slotsP, 0, (size_t)NWG * 16 * 4, stream);

    k_sched<<<1, 64, 0, stream>>>(trans, tbcode, s1code, s2code, wkA, fcode, anyred);
    k_pack_a<<<(8 * 896 * 64 + 255) / 256, 256, 0, stream>>>(Wb, W1, W2, Wl, blv, WAb, blA);
    k_pack_b<<<(16 * 640 * 128 + 255) / 256, 256, 0, stream>>>(WLm, WR, WT, WBb);
    k_spinn<<<NWG, NT, 0, stream>>>(bufh, bufc, WAb, blA, WBb, bLv,
                                    tbcode, s1code, s2code, wkA, fcode, anyred,
                                    th, tc, redh, redc, slots, slotsP, out);
}

// Round 13
// 827.856 us; speedup vs baseline: 1.4495x; 1.0745x over previous
//
#include <hip/hip_runtime.h>
#include <cstdint>
#include <cstddef>

#define NB 64      // batch
#define LN 48      // buffer length
#define DN 256     // hidden dim
#define TKN 128    // tracker dim
#define TN 95      // steps
#define RMAX 48    // max reduces per batch
#define GA 512     // 4*TK
#define GR 1280    // 5*D
#define NWG 256
#define NT 512

__device__ __forceinline__ float sigf(float x) { return 1.0f / (1.0f + expf(-x)); }

__device__ __forceinline__ float bf2f(unsigned u16) {
    unsigned x = u16 << 16;
    return __builtin_bit_cast(float, x);
}
__device__ __forceinline__ unsigned short f2bf(float f) {
    unsigned x = __builtin_bit_cast(unsigned, f);
    unsigned r = (x + 0x7FFFu + ((x >> 16) & 1u)) >> 16;
    return (unsigned short)r;
}

// coherent (sc1) access — bypasses non-coherent per-XCD L2 (verified r4-r12)
__device__ __forceinline__ float cohLd(const float* p) {
    return __hip_atomic_load(p, __ATOMIC_RELAXED, __HIP_MEMORY_SCOPE_AGENT);
}
__device__ __forceinline__ void cohSt(float* p, float v) {
    __hip_atomic_store(p, v, __ATOMIC_RELAXED, __HIP_MEMORY_SCOPE_AGENT);
}
__device__ __forceinline__ unsigned cohLdU(const unsigned* p) {
    return __hip_atomic_load(p, __ATOMIC_RELAXED, __HIP_MEMORY_SCOPE_AGENT);
}
__device__ __forceinline__ void cohStU(unsigned* p, unsigned v) {
    __hip_atomic_store(p, v, __ATOMIC_RELAXED, __HIP_MEMORY_SCOPE_AGENT);
}

// group sync: the 16 WGs sharing grp = wg>>4 (4 batches) all-observe each other.
// Dependency audit (r13): th2 (pair-scope ⊂ group), redh/redc (quad-scope = group),
// WT-part th2 (two pairs of the quad = group) — no cross-group data flow exists.
// __syncthreads() drains vmcnt(0) before the arrival store (verified r4-r12).
__device__ __forceinline__ void qsync(unsigned* slots, int grp, unsigned& qph) {
    __syncthreads();
    qph += 1;
    if (threadIdx.x == 0) cohStU(&slots[blockIdx.x * 16], qph);
    if (threadIdx.x < 16) {
        while (cohLdU(&slots[(grp * 16 + threadIdx.x) * 16]) < qph)
            __builtin_amdgcn_s_sleep(1);
    }
    asm volatile("" ::: "memory");
    __syncthreads();
}

// pair-scoped sync (shift steps): only the 8 WGs {8u..8u+7} sharing batch-pair u
// exchange th2 (verified r12).
__device__ __forceinline__ void psync(unsigned* slotsP, int u, int xcd, unsigned& pph) {
    __syncthreads();
    pph += 1;
    if (threadIdx.x == 0) cohStU(&slotsP[(u * 8 + xcd) * 16], pph);
    if (threadIdx.x < 8) {
        while (cohLdU(&slotsP[(u * 8 + threadIdx.x) * 16]) < pph)
            __builtin_amdgcn_s_sleep(1);
    }
    asm volatile("" ::: "memory");
    __syncthreads();
}

// ---------------- schedule builder (verified r1-r12) ------------------------
__global__ void k_sched(const int* __restrict__ trans,
                        int* __restrict__ tbcode, int* __restrict__ s1code,
                        int* __restrict__ s2code, int* __restrict__ wkA,
                        int* __restrict__ fcode, int* __restrict__ anyred) {
    __shared__ int tg[NB][LN];
    int b = threadIdx.x;
    if (b >= NB) return;
    for (int i = 0; i < LN; ++i) tg[b][i] = -1;
    int sp = 0, bp = 0, k = 0;
    for (int t = 0; t < TN; ++t) {
        int tr = trans[b * TN + t];
        int shift = (tr == 0);
        int tb = (bp < LN) ? bp : -1;
        tbcode[t * NB + b] = tb;
        int i1 = sp - 1; if (i1 < 0) i1 = 0; if (i1 > LN - 1) i1 = LN - 1;
        int i2 = sp - 2; if (i2 < 0) i2 = 0; if (i2 > LN - 1) i2 = LN - 1;
        s1code[t * NB + b] = (sp >= 1) ? tg[b][i1] : -1;
        s2code[t * NB + b] = (sp >= 2) ? tg[b][i2] : -1;
        int wk_t;
        if (shift) {
            wk_t = -1;
            if (sp >= 0 && sp < LN) tg[b][sp] = tb;
            sp = sp + 1;
            bp = bp + 1;
        } else {
            wk_t = k;
            int pos = sp - 2; if (pos < 0) pos = 0;
            if (pos < LN) tg[b][pos] = 1000 + k;
            k++;
            sp = sp - 1; if (sp < 0) sp = 0;
        }
        wkA[t * NB + b] = wk_t;
        unsigned long long m = __ballot(wk_t >= 0);
        if (b == 0) anyred[t] = (m != 0ull) ? 1 : 0;
    }
    int fi = sp - 1; if (fi < 0) fi = 0; if (fi > LN - 1) fi = LN - 1;
    fcode[b] = tg[b][fi];
}

// ---- P1 pack (bf16): WAb[slice8][k896][64 cols]; packed col p = j*4+gate ----
__global__ __launch_bounds__(256) void k_pack_a(
    const float* __restrict__ Wb, const float* __restrict__ W1,
    const float* __restrict__ W2, const float* __restrict__ Wl,
    const float* __restrict__ blv,
    unsigned short* __restrict__ WAb, float* __restrict__ blA) {
    int idx = blockIdx.x * 256 + threadIdx.x;
    if (idx < 8 * 896 * 64) {
        int s = idx / (896 * 64);
        int r = idx % (896 * 64);
        int k = r >> 6, c = r & 63;
        int p = s * 64 + c;
        int j = p >> 2, q = p & 3;
        int sc = q * 128 + j;
        float v;
        if (k < 256)      v = Wb[(size_t)k * GA + sc];
        else if (k < 512) v = W1[(size_t)(k - 256) * GA + sc];
        else if (k < 768) v = W2[(size_t)(k - 512) * GA + sc];
        else              v = Wl[(size_t)(k - 768) * GA + sc];
        WAb[idx] = f2bf(v);
    }
    if (idx < 512) {
        int j = idx >> 2, q = idx & 3;
        blA[idx] = blv[q * 128 + j];
    }
}

// ---- P2 pack (bf16): WBb[slice16][k640][jj16*8slots]; slot g<5 real ---------
__global__ __launch_bounds__(256) void k_pack_b(
    const float* __restrict__ WLm, const float* __restrict__ WRm,
    const float* __restrict__ WTm, unsigned short* __restrict__ WBb) {
    int idx = blockIdx.x * 256 + threadIdx.x;
    if (idx >= 16 * 640 * 128) return;
    int s = idx / (640 * 128);
    int r = idx % (640 * 128);
    int k = r >> 7, cc = r & 127;
    int jj = cc >> 3, g = cc & 7;
    float v = 0.f;
    if (g < 5) {
        int sc = g * 256 + s * 16 + jj;
        if (k < 256)      v = WLm[(size_t)k * GR + sc];
        else if (k < 512) v = WRm[(size_t)(k - 256) * GR + sc];
        else              v = WTm[(size_t)(k - 512) * GR + sc];
    }
    WBb[idx] = f2bf(v);
}

// ---------------- persistent full-scan kernel (r12 structure) ---------------
__global__ __launch_bounds__(NT, 1) void k_spinn(
    const float* __restrict__ bufh, const float* __restrict__ bufc,
    const unsigned short* __restrict__ WAb, const float* __restrict__ blA,
    const unsigned short* __restrict__ WBb, const float* __restrict__ bLv,
    const int* __restrict__ tbcode, const int* __restrict__ s1code,
    const int* __restrict__ s2code, const int* __restrict__ wkA,
    const int* __restrict__ fcode, const int* __restrict__ anyred,
    float* __restrict__ th, float* __restrict__ tc,
    float* __restrict__ redh, float* __restrict__ redc,
    unsigned* __restrict__ slots, unsigned* __restrict__ slotsP,
    float* __restrict__ out) {
    const int wg = blockIdx.x;
    const int tid = threadIdx.x;
    const int lane = tid & 63;
    const int w = tid >> 6;                 // 8 waves
    unsigned qph = 0, pph = 0;

    const int xcd = wg & 7;
    const int u = wg >> 3;                  // 0..31
    const int grp = wg >> 4;                // 16-WG group (4 batches)
    const int jg = xcd;                     // P1 64-col slice (114KB bf16, L2/XCD)
    const int bg1 = u;                      // P1: 2 b (pair u)
    const int bg2 = u >> 1;                 // P2: 4 b (== grp)
    const int jgw = (u & 1) + 2 * xcd;      // P2 slice (160KB bf16; 2/XCD)

    __shared__ float xs[2][896];            // P1 input
    __shared__ float part1[2][64][33];      // P1 partials (2-way bank max)
    __shared__ float gsum[2][64];
    __shared__ float xs2[4][16][33];        // P2 s-part input, ks-major pad 33
    __shared__ float part2[16][16][21];     // P2 partials, padded
    __shared__ float gsum2[4][5][16];
    __shared__ float xst[4][128];           // th2 for WT part

    for (int t = 0; t < TN; ++t) {
        const int par = t & 1;
        const bool red = anyred[t] != 0;

        // ============ stage: P1 xs (448 f4) + P2s xs2 (512 f4) ============
        int ngroups = red ? 960 : 448;
        for (int g = tid; g < ngroups; g += NT) {
            if (g < 448) {
                int row = g & 1, k0 = (g >> 1) * 4;
                int b = bg1 * 2 + row;
                float4 v = {0.f, 0.f, 0.f, 0.f};
                if (k0 < 256) {
                    int c = tbcode[t * NB + b];
                    if (c >= 0) v = *(const float4*)&bufh[((size_t)b * LN + c) * DN + k0];
                } else if (k0 < 512) {
                    int c = s1code[t * NB + b];
                    int kk = k0 - 256;
                    if (c >= 1000) {
                        const float* p = &redh[((size_t)(c - 1000) * NB + b) * DN + kk];
                        v.x = cohLd(p); v.y = cohLd(p + 1); v.z = cohLd(p + 2); v.w = cohLd(p + 3);
                    } else if (c >= 0) v = *(const float4*)&bufh[((size_t)b * LN + c) * DN + kk];
                } else if (k0 < 768) {
                    int c = s2code[t * NB + b];
                    int kk = k0 - 512;
                    if (c >= 1000) {
                        const float* p = &redh[((size_t)(c - 1000) * NB + b) * DN + kk];
                        v.x = cohLd(p); v.y = cohLd(p + 1); v.z = cohLd(p + 2); v.w = cohLd(p + 3);
                    } else if (c >= 0) v = *(const float4*)&bufh[((size_t)b * LN + c) * DN + kk];
                } else {
                    const float* p = &th[((size_t)par * NB + b) * TKN + (k0 - 768)];
                    v.x = cohLd(p); v.y = cohLd(p + 1); v.z = cohLd(p + 2); v.w = cohLd(p + 3);
                }
                *(float4*)&xs[row][k0] = v;
            } else {
                int g2 = g - 448;
                int row = g2 & 3, k0 = (g2 >> 2) * 4;
                int b = bg2 * 4 + row;
                float4 v = {0.f, 0.f, 0.f, 0.f};
                if (k0 < 256) {
                    int c = s2code[t * NB + b];
                    if (c >= 1000) {
                        const float* p = &redh[((size_t)(c - 1000) * NB + b) * DN + k0];
                        v.x = cohLd(p); v.y = cohLd(p + 1); v.z = cohLd(p + 2); v.w = cohLd(p + 3);
                    } else if (c >= 0) v = *(const float4*)&bufh[((size_t)b * LN + c) * DN + k0];
                } else {
                    int c = s1code[t * NB + b];
                    int kk = k0 - 256;
                    if (c >= 1000) {
                        const float* p = &redh[((size_t)(c - 1000) * NB + b) * DN + kk];
                        v.x = cohLd(p); v.y = cohLd(p + 1); v.z = cohLd(p + 2); v.w = cohLd(p + 3);
                    } else if (c >= 0) v = *(const float4*)&bufh[((size_t)b * LN + c) * DN + kk];
                }
                *(float4*)&xs2[row][k0 >> 5][k0 & 31] = v;
            }
        }
        __syncthreads();

        // ============ concurrent GEMMs: waves 0-3 P1, waves 4-7 P2s ============
        float acc[5][4];   // P2 accumulators live across sync A in registers
        if (w < 4) {
            int c8 = lane & 7, kq = lane >> 3;
            int kbase = w * 224;
            const uint4* wp = (const uint4*)WAb + ((size_t)(jg * 896 + kbase + kq) * 8) + c8;
            float a0[8], a1[8];
            #pragma unroll
            for (int cc = 0; cc < 8; ++cc) { a0[cc] = 0.f; a1[cc] = 0.f; }
            #pragma unroll 4
            for (int i = 0; i < 28; ++i) {
                uint4 wv = wp[(size_t)i * 64];          // wave: 1KB contiguous
                int k = kbase + kq + i * 8;
                float x0 = xs[0][k], x1 = xs[1][k];
                float wf0 = bf2f(wv.x & 0xFFFF), wf1 = bf2f(wv.x >> 16);
                float wf2 = bf2f(wv.y & 0xFFFF), wf3 = bf2f(wv.y >> 16);
                float wf4 = bf2f(wv.z & 0xFFFF), wf5 = bf2f(wv.z >> 16);
                float wf6 = bf2f(wv.w & 0xFFFF), wf7 = bf2f(wv.w >> 16);
                a0[0] += x0 * wf0; a1[0] += x1 * wf0;
                a0[1] += x0 * wf1; a1[1] += x1 * wf1;
                a0[2] += x0 * wf2; a1[2] += x1 * wf2;
                a0[3] += x0 * wf3; a1[3] += x1 * wf3;
                a0[4] += x0 * wf4; a1[4] += x1 * wf4;
                a0[5] += x0 * wf5; a1[5] += x1 * wf5;
                a0[6] += x0 * wf6; a1[6] += x1 * wf6;
                a0[7] += x0 * wf7; a1[7] += x1 * wf7;
            }
            int ks = w * 8 + kq;
            #pragma unroll
            for (int cc = 0; cc < 8; ++cc) {
                part1[0][c8 * 8 + cc][ks] = a0[cc];
                part1[1][c8 * 8 + cc][ks] = a1[cc];
            }
        } else if (red) {
            int t2 = tid - 256, jj = t2 & 15, ks = t2 >> 4;   // 16 j x 16 kslices
            #pragma unroll
            for (int g = 0; g < 5; ++g)
                #pragma unroll
                for (int b4 = 0; b4 < 4; ++b4) acc[g][b4] = 0.f;
            const uint4* wb = (const uint4*)WBb + ((size_t)(jgw * 640 + ks * 32) * 16) + jj;
            #pragma unroll 4
            for (int i = 0; i < 32; ++i) {
                uint4 wv = wb[(size_t)i * 16];          // 8 slots (5 real) = 16B
                float w0 = bf2f(wv.x & 0xFFFF), w1 = bf2f(wv.x >> 16);
                float w2 = bf2f(wv.y & 0xFFFF), w3 = bf2f(wv.y >> 16);
                float w4 = bf2f(wv.z & 0xFFFF);
                int kb = (ks * 32 + i) >> 5, ko = i;    // ks-major layout
                float x0 = xs2[0][kb][ko], x1 = xs2[1][kb][ko];
                float x2 = xs2[2][kb][ko], x3 = xs2[3][kb][ko];
                acc[0][0] += x0 * w0; acc[1][0] += x0 * w1; acc[2][0] += x0 * w2; acc[3][0] += x0 * w3; acc[4][0] += x0 * w4;
                acc[0][1] += x1 * w0; acc[1][1] += x1 * w1; acc[2][1] += x1 * w2; acc[3][1] += x1 * w3; acc[4][1] += x1 * w4;
                acc[0][2] += x2 * w0; acc[1][2] += x2 * w1; acc[2][2] += x2 * w2; acc[3][2] += x2 * w3; acc[4][2] += x2 * w4;
                acc[0][3] += x3 * w0; acc[1][3] += x3 * w1; acc[2][3] += x3 * w2; acc[3][3] += x3 * w3; acc[4][3] += x3 * w4;
            }
        }
        __syncthreads();

        // ============ P1 reduce + tracker LSTM ============
        if (tid < 128) {
            int b = tid & 1, col = tid >> 1;
            float s = 0.f;
            #pragma unroll
            for (int ks = 0; ks < 32; ++ks) s += part1[b][col][ks];
            if (t > 0) s += blA[jg * 64 + col];
            gsum[b][col] = s;
        }
        __syncthreads();
        if (tid < 32) {
            int bl_ = tid >> 4, jj = tid & 15;
            int b = bg1 * 2 + bl_;
            int j = jg * 16 + jj;
            float4 g4 = *(const float4*)&gsum[bl_][jj * 4];     // a,i,f,o
            float tco = tc[((size_t)par * NB + b) * TKN + j];
            float c2v = tanhf(g4.x) * sigf(g4.y) + sigf(g4.z) * tco;
            float h2 = sigf(g4.w) * tanhf(c2v);
            tc[((size_t)(par ^ 1) * NB + b) * TKN + j] = c2v;
            cohSt(&th[((size_t)(par ^ 1) * NB + b) * TKN + j], h2);
        }

        if (!red) {
            // shift step: only the 8 WGs of pair u exchange th2 — pair sync
            psync(slotsP, u, xcd, pph);
            continue;
        }
        qsync(slots, grp, qph);   // sync A: th2 visible within 16-WG group

        // ============ WT part (K=128) + reduce + TreeLSTM ============
        {
            int b4 = tid >> 7, kk = tid & 127;
            xst[b4][kk] = cohLd(&th[((size_t)(par ^ 1) * NB + bg2 * 4 + b4) * TKN + kk]);
        }
        __syncthreads();
        if (w >= 4) {
            int t2 = tid - 256, jj = t2 & 15, ks = t2 >> 4;
            const uint4* wb = (const uint4*)WBb + ((size_t)(jgw * 640 + 512 + ks * 8) * 16) + jj;
            #pragma unroll
            for (int i = 0; i < 8; ++i) {
                uint4 wv = wb[(size_t)i * 16];
                float w0 = bf2f(wv.x & 0xFFFF), w1 = bf2f(wv.x >> 16);
                float w2 = bf2f(wv.y & 0xFFFF), w3 = bf2f(wv.y >> 16);
                float w4 = bf2f(wv.z & 0xFFFF);
                int kk2 = ks * 8 + i;
                float x0 = xst[0][kk2], x1 = xst[1][kk2], x2 = xst[2][kk2], x3 = xst[3][kk2];
                acc[0][0] += x0 * w0; acc[1][0] += x0 * w1; acc[2][0] += x0 * w2; acc[3][0] += x0 * w3; acc[4][0] += x0 * w4;
                acc[0][1] += x1 * w0; acc[1][1] += x1 * w1; acc[2][1] += x1 * w2; acc[3][1] += x1 * w3; acc[4][1] += x1 * w4;
                acc[0][2] += x2 * w0; acc[1][2] += x2 * w1; acc[2][2] += x2 * w2; acc[3][2] += x2 * w3; acc[4][2] += x2 * w4;
                acc[0][3] += x3 * w0; acc[1][3] += x3 * w1; acc[2][3] += x3 * w2; acc[3][3] += x3 * w3; acc[4][3] += x3 * w4;
            }
            #pragma unroll
            for (int g = 0; g < 5; ++g)
                #pragma unroll
                for (int b4 = 0; b4 < 4; ++b4)
                    part2[ks][jj][g * 4 + b4] = acc[g][b4];
        }
        __syncthreads();
        if (tid < 320) {
            int g = tid >> 6, r = tid & 63;
            int bl_ = r >> 4, jj = r & 15;
            float s = 0.f;
            #pragma unroll
            for (int ks = 0; ks < 16; ++ks) s += part2[ks][jj][g * 4 + bl_];
            gsum2[bl_][g][jj] = s;
        }
        __syncthreads();
        if (tid < 64) {
            int bl_ = tid >> 4, jj = tid & 15;
            int b = bg2 * 4 + bl_;
            int wk = wkA[t * NB + b];
            if (wk >= 0) {
                int j = jgw * 16 + jj;
                float ga  = gsum2[bl_][0][jj] + bLv[0 * 256 + j];
                float gi  = gsum2[bl_][1][jj] + bLv[1 * 256 + j];
                float gf1 = gsum2[bl_][2][jj] + bLv[2 * 256 + j];
                float gf2 = gsum2[bl_][3][jj] + bLv[3 * 256 + j];
                float go  = gsum2[bl_][4][jj] + bLv[4 * 256 + j];
                int c1 = s1code[t * NB + b], c2 = s2code[t * NB + b];
                float s2cv = (c2 == -1) ? 0.f
                            : ((c2 >= 1000) ? redc[((size_t)(c2 - 1000) * NB + b) * DN + j]
                                            : bufc[((size_t)b * LN + c2) * DN + j]);
                float s1cv = (c1 == -1) ? 0.f
                            : ((c1 >= 1000) ? redc[((size_t)(c1 - 1000) * NB + b) * DN + j]
                                            : bufc[((size_t)b * LN + c1) * DN + j]);
                float cc = tanhf(ga) * sigf(gi) + sigf(gf1) * s2cv + sigf(gf2) * s1cv;
                float hh = sigf(go) * tanhf(cc);
                cohSt(&redh[((size_t)wk * NB + b) * DN + j], hh);   // cross-WG
                redc[((size_t)wk * NB + b) * DN + j] = cc;          // owner-stable
            }
        }
        qsync(slots, grp, qph);   // sync C: redh visible within 16-WG group
    }

    // ===== final output: P2-owner (b,j) writes its slice =====
    if (tid < 64) {
        int bl_ = tid >> 4, jj = tid & 15;
        int b = bg2 * 4 + bl_;
        int j = jgw * 16 + jj;
        int c = fcode[b];
        float h = 0.f, cv = 0.f;
        if (c >= 1000) {
            h  = cohLd(&redh[((size_t)(c - 1000) * NB + b) * DN + j]);
            cv = redc[((size_t)(c - 1000) * NB + b) * DN + j];
        } else if (c >= 0) {
            h  = bufh[((size_t)b * LN + c) * DN + j];
            cv = bufc[((size_t)b * LN + c) * DN + j];
        }
        out[(size_t)b * 2 * DN + j]      = h;
        out[(size_t)b * 2 * DN + DN + j] = cv;
    }
}

extern "C" void kernel_launch(void* const* d_in, const int* in_sizes, int n_in,
                              void* d_out, int out_size, void* d_ws, size_t ws_size,
                              hipStream_t stream) {
    const float* bufh = (const float*)d_in[0];
    const float* bufc = (const float*)d_in[1];
    const float* Wb   = (const float*)d_in[2];
    const float* W1   = (const float*)d_in[3];
    const float* W2   = (const float*)d_in[4];
    const float* Wl   = (const float*)d_in[5];
    const float* blv  = (const float*)d_in[6];
    const float* WLm  = (const float*)d_in[7];
    const float* bLv  = (const float*)d_in[8];
    const float* WR   = (const float*)d_in[9];
    const float* WT   = (const float*)d_in[10];
    const int* trans  = (const int*)d_in[11];
    float* out = (float*)d_out;

    char* p = (char*)d_ws;
    auto carve = [&](size_t bytes) -> char* {
        char* r = p;
        p += (bytes + 255) & ~(size_t)255;
        return r;
    };
    int* tbcode = (int*)carve((size_t)TN * NB * 4);
    int* s1code = (int*)carve((size_t)TN * NB * 4);
    int* s2code = (int*)carve((size_t)TN * NB * 4);
    int* wkA    = (int*)carve((size_t)TN * NB * 4);
    int* fcode  = (int*)carve((size_t)NB * 4);
    int* anyred = (int*)carve((size_t)TN * 4);
    float* th   = (float*)carve((size_t)2 * NB * TKN * 4);
    float* tc   = (float*)carve((size_t)2 * NB * TKN * 4);
    float* redh = (float*)carve((size_t)RMAX * NB * DN * 4);
    float* redc = (float*)carve((size_t)RMAX * NB * DN * 4);
    unsigned short* WAb = (unsigned short*)carve((size_t)8 * 896 * 64 * 2);
    float* blA  = (float*)carve((size_t)512 * 4);
    unsigned short* WBb = (unsigned short*)carve((size_t)16 * 640 * 128 * 2);
    unsigned* slots  = (unsigned*)carve((size_t)NWG * 16 * 4);
    unsigned* slotsP = (unsigned*)carve((size_t)NWG * 16 * 4);

    hipMemsetAsync(th, 0, (size_t)2 * NB * TKN * 4, stream);
    hipMemsetAsync(tc, 0, (size_t)2 * NB * TKN * 4, stream);
    hipMemsetAsync(slots, 0, (size_t)NWG * 16 * 4, stream);
    hipMemsetAsync(slotsP, 0, (size_t)NWG * 16 * 4, stream);

    k_sched<<<1, 64, 0, stream>>>(trans, tbcode, s1code, s2code, wkA, fcode, anyred);
    k_pack_a<<<(8 * 896 * 64 + 255) / 256, 256, 0, stream>>>(Wb, W1, W2, Wl, blv, WAb, blA);
    k_pack_b<<<(16 * 640 * 128 + 255) / 256, 256, 0, stream>>>(WLm, WR, WT, WBb);
    k_spinn<<<NWG, NT, 0, stream>>>(bufh, bufc, WAb, blA, WBb, bLv,
                                    tbcode, s1code, s2code, wkA, fcode, anyred,
                                    th, tc, redh, redc, slots, slotsP, out);
}

// Round 14
// 720.842 us; speedup vs baseline: 1.6647x; 1.1485x over previous
//
#include <hip/hip_runtime.h>
#include <cstdint>
#include <cstddef>

#define NB 64      // batch
#define LN 48      // buffer length
#define DN 256     // hidden dim
#define TKN 128    // tracker dim
#define TN 95      // steps
#define RMAX 48    // max reduces per batch
#define GA 512     // 4*TK
#define GR 1280    // 5*D
#define NWG 256
#define NT 512

__device__ __forceinline__ float sigf(float x) { return 1.0f / (1.0f + expf(-x)); }

__device__ __forceinline__ float bf2f(unsigned u16) {
    unsigned x = u16 << 16;
    return __builtin_bit_cast(float, x);
}
__device__ __forceinline__ unsigned short f2bf(float f) {
    unsigned x = __builtin_bit_cast(unsigned, f);
    unsigned r = (x + 0x7FFFu + ((x >> 16) & 1u)) >> 16;
    return (unsigned short)r;
}

// coherent (sc1) access — bypasses non-coherent per-XCD L2 (verified r4-r13)
__device__ __forceinline__ float cohLd(const float* p) {
    return __hip_atomic_load(p, __ATOMIC_RELAXED, __HIP_MEMORY_SCOPE_AGENT);
}
__device__ __forceinline__ void cohSt(float* p, float v) {
    __hip_atomic_store(p, v, __ATOMIC_RELAXED, __HIP_MEMORY_SCOPE_AGENT);
}
__device__ __forceinline__ unsigned cohLdU(const unsigned* p) {
    return __hip_atomic_load(p, __ATOMIC_RELAXED, __HIP_MEMORY_SCOPE_AGENT);
}
__device__ __forceinline__ void cohStU(unsigned* p, unsigned v) {
    __hip_atomic_store(p, v, __ATOMIC_RELAXED, __HIP_MEMORY_SCOPE_AGENT);
}

// group sync: the 16 WGs sharing grp = wg>>4 (4 batches) all-observe each other
// (dependency audit r13: all cross-WG edges are group-internal). __syncthreads()
// drains vmcnt(0) before the arrival store (verified r4-r13).
__device__ __forceinline__ void qsync(unsigned* slots, int grp, unsigned& qph) {
    __syncthreads();
    qph += 1;
    if (threadIdx.x == 0) cohStU(&slots[blockIdx.x * 16], qph);
    if (threadIdx.x < 16) {
        while (cohLdU(&slots[(grp * 16 + threadIdx.x) * 16]) < qph)
            __builtin_amdgcn_s_sleep(1);
    }
    asm volatile("" ::: "memory");
    __syncthreads();
}

// pair-scoped sync (shift steps): only the 8 WGs {8u..8u+7} sharing batch-pair u
// exchange th2 (verified r12/r13).
__device__ __forceinline__ void psync(unsigned* slotsP, int u, int xcd, unsigned& pph) {
    __syncthreads();
    pph += 1;
    if (threadIdx.x == 0) cohStU(&slotsP[(u * 8 + xcd) * 16], pph);
    if (threadIdx.x < 8) {
        while (cohLdU(&slotsP[(u * 8 + threadIdx.x) * 16]) < pph)
            __builtin_amdgcn_s_sleep(1);
    }
    asm volatile("" ::: "memory");
    __syncthreads();
}

// ---------------- schedule builder (verified r1-r13) ------------------------
__global__ void k_sched(const int* __restrict__ trans,
                        int* __restrict__ tbcode, int* __restrict__ s1code,
                        int* __restrict__ s2code, int* __restrict__ wkA,
                        int* __restrict__ fcode, int* __restrict__ anyred) {
    __shared__ int tg[NB][LN];
    int b = threadIdx.x;
    if (b >= NB) return;
    for (int i = 0; i < LN; ++i) tg[b][i] = -1;
    int sp = 0, bp = 0, k = 0;
    for (int t = 0; t < TN; ++t) {
        int tr = trans[b * TN + t];
        int shift = (tr == 0);
        int tb = (bp < LN) ? bp : -1;
        tbcode[t * NB + b] = tb;
        int i1 = sp - 1; if (i1 < 0) i1 = 0; if (i1 > LN - 1) i1 = LN - 1;
        int i2 = sp - 2; if (i2 < 0) i2 = 0; if (i2 > LN - 1) i2 = LN - 1;
        s1code[t * NB + b] = (sp >= 1) ? tg[b][i1] : -1;
        s2code[t * NB + b] = (sp >= 2) ? tg[b][i2] : -1;
        int wk_t;
        if (shift) {
            wk_t = -1;
            if (sp >= 0 && sp < LN) tg[b][sp] = tb;
            sp = sp + 1;
            bp = bp + 1;
        } else {
            wk_t = k;
            int pos = sp - 2; if (pos < 0) pos = 0;
            if (pos < LN) tg[b][pos] = 1000 + k;
            k++;
            sp = sp - 1; if (sp < 0) sp = 0;
        }
        wkA[t * NB + b] = wk_t;
        unsigned long long m = __ballot(wk_t >= 0);
        if (b == 0) anyred[t] = (m != 0ull) ? 1 : 0;
    }
    int fi = sp - 1; if (fi < 0) fi = 0; if (fi > LN - 1) fi = LN - 1;
    fcode[b] = tg[b][fi];
}

// ---- P1 pack (bf16): WAb[slice8][k896][64 cols]; packed col p = j*4+gate ----
__global__ __launch_bounds__(256) void k_pack_a(
    const float* __restrict__ Wb, const float* __restrict__ W1,
    const float* __restrict__ W2, const float* __restrict__ Wl,
    const float* __restrict__ blv,
    unsigned short* __restrict__ WAb, float* __restrict__ blA) {
    int idx = blockIdx.x * 256 + threadIdx.x;
    if (idx < 8 * 896 * 64) {
        int s = idx / (896 * 64);
        int r = idx % (896 * 64);
        int k = r >> 6, c = r & 63;
        int p = s * 64 + c;
        int j = p >> 2, q = p & 3;
        int sc = q * 128 + j;
        float v;
        if (k < 256)      v = Wb[(size_t)k * GA + sc];
        else if (k < 512) v = W1[(size_t)(k - 256) * GA + sc];
        else if (k < 768) v = W2[(size_t)(k - 512) * GA + sc];
        else              v = Wl[(size_t)(k - 768) * GA + sc];
        WAb[idx] = f2bf(v);
    }
    if (idx < 512) {
        int j = idx >> 2, q = idx & 3;
        blA[idx] = blv[q * 128 + j];
    }
}

// ---- P2 pack (bf16): WBb[slice16][k640][jj16*8slots]; slot g<5 real ---------
__global__ __launch_bounds__(256) void k_pack_b(
    const float* __restrict__ WLm, const float* __restrict__ WRm,
    const float* __restrict__ WTm, unsigned short* __restrict__ WBb) {
    int idx = blockIdx.x * 256 + threadIdx.x;
    if (idx >= 16 * 640 * 128) return;
    int s = idx / (640 * 128);
    int r = idx % (640 * 128);
    int k = r >> 7, cc = r & 127;
    int jj = cc >> 3, g = cc & 7;
    float v = 0.f;
    if (g < 5) {
        int sc = g * 256 + s * 16 + jj;
        if (k < 256)      v = WLm[(size_t)k * GR + sc];
        else if (k < 512) v = WRm[(size_t)(k - 256) * GR + sc];
        else              v = WTm[(size_t)(k - 512) * GR + sc];
    }
    WBb[idx] = f2bf(v);
}

// ---------------- persistent full-scan kernel (r13 structure + 3 edits) -----
__global__ __launch_bounds__(NT, 1) void k_spinn(
    const float* __restrict__ bufh, const float* __restrict__ bufc,
    const unsigned short* __restrict__ WAb, const float* __restrict__ blA,
    const unsigned short* __restrict__ WBb, const float* __restrict__ bLv,
    const int* __restrict__ tbcode, const int* __restrict__ s1code,
    const int* __restrict__ s2code, const int* __restrict__ wkA,
    const int* __restrict__ fcode, const int* __restrict__ anyred,
    float* __restrict__ th, float* __restrict__ tc,
    float* __restrict__ redh, float* __restrict__ redc,
    unsigned* __restrict__ slots, unsigned* __restrict__ slotsP,
    float* __restrict__ out) {
    const int wg = blockIdx.x;
    const int tid = threadIdx.x;
    const int lane = tid & 63;
    const int w = tid >> 6;                 // 8 waves
    unsigned qph = 0, pph = 0;

    const int xcd = wg & 7;
    const int u = wg >> 3;                  // 0..31
    const int grp = wg >> 4;                // 16-WG group (4 batches)
    const int jg = xcd;                     // P1 64-col slice (114KB bf16, L2/XCD)
    const int bg1 = u;                      // P1: 2 b (pair u)
    const int bg2 = u >> 1;                 // P2: 4 b (== grp)
    const int jgw = (u & 1) + 2 * xcd;      // P2 slice (160KB bf16; 2/XCD)

    __shared__ float xs[2][896];            // P1 input
    __shared__ float part1[2][64][65];      // P1 partials: 64 slots (8-wave shift)
    __shared__ float gsum[2][64];
    __shared__ float xs2[4][16][33];        // P2 s-part input, ks-major pad 33
    __shared__ float part2[16][16][21];     // P2 partials, padded
    __shared__ float gsum2[4][5][16];
    __shared__ float xst[4][128];           // th2 for WT part
    __shared__ float cellv[2][4][17];       // prefetched s2c/s1c cell values

    for (int t = 0; t < TN; ++t) {
        const int par = t & 1;
        const bool red = anyred[t] != 0;

        // ==== stage: P1 xs (448 f4) + P2s xs2 (512 f4) + cell prefetch (128) ====
        int ngroups = red ? 1088 : 448;
        for (int g = tid; g < ngroups; g += NT) {
            if (g < 448) {
                int row = g & 1, k0 = (g >> 1) * 4;
                int b = bg1 * 2 + row;
                float4 v = {0.f, 0.f, 0.f, 0.f};
                if (k0 < 256) {
                    int c = tbcode[t * NB + b];
                    if (c >= 0) v = *(const float4*)&bufh[((size_t)b * LN + c) * DN + k0];
                } else if (k0 < 512) {
                    int c = s1code[t * NB + b];
                    int kk = k0 - 256;
                    if (c >= 1000) {
                        const float* p = &redh[((size_t)(c - 1000) * NB + b) * DN + kk];
                        v.x = cohLd(p); v.y = cohLd(p + 1); v.z = cohLd(p + 2); v.w = cohLd(p + 3);
                    } else if (c >= 0) v = *(const float4*)&bufh[((size_t)b * LN + c) * DN + kk];
                } else if (k0 < 768) {
                    int c = s2code[t * NB + b];
                    int kk = k0 - 512;
                    if (c >= 1000) {
                        const float* p = &redh[((size_t)(c - 1000) * NB + b) * DN + kk];
                        v.x = cohLd(p); v.y = cohLd(p + 1); v.z = cohLd(p + 2); v.w = cohLd(p + 3);
                    } else if (c >= 0) v = *(const float4*)&bufh[((size_t)b * LN + c) * DN + kk];
                } else {
                    const float* p = &th[((size_t)par * NB + b) * TKN + (k0 - 768)];
                    v.x = cohLd(p); v.y = cohLd(p + 1); v.z = cohLd(p + 2); v.w = cohLd(p + 3);
                }
                *(float4*)&xs[row][k0] = v;
            } else if (g < 960) {
                int g2 = g - 448;
                int row = g2 & 3, k0 = (g2 >> 2) * 4;
                int b = bg2 * 4 + row;
                float4 v = {0.f, 0.f, 0.f, 0.f};
                if (k0 < 256) {
                    int c = s2code[t * NB + b];
                    if (c >= 1000) {
                        const float* p = &redh[((size_t)(c - 1000) * NB + b) * DN + k0];
                        v.x = cohLd(p); v.y = cohLd(p + 1); v.z = cohLd(p + 2); v.w = cohLd(p + 3);
                    } else if (c >= 0) v = *(const float4*)&bufh[((size_t)b * LN + c) * DN + k0];
                } else {
                    int c = s1code[t * NB + b];
                    int kk = k0 - 256;
                    if (c >= 1000) {
                        const float* p = &redh[((size_t)(c - 1000) * NB + b) * DN + kk];
                        v.x = cohLd(p); v.y = cohLd(p + 1); v.z = cohLd(p + 2); v.w = cohLd(p + 3);
                    } else if (c >= 0) v = *(const float4*)&bufh[((size_t)b * LN + c) * DN + kk];
                }
                *(float4*)&xs2[row][k0 >> 5][k0 & 31] = v;
            } else {
                // cell prefetch: s2c (sel=0) / s1c (sel=1) for TreeLSTM tail.
                // redc entries are produced by THIS WG (owner-stable), bufc is input.
                int g3 = g - 960;
                int sel = g3 >> 6, r = g3 & 63;
                int bl_ = r >> 4, jj = r & 15;
                int b = bg2 * 4 + bl_;
                int j = jgw * 16 + jj;
                int c = (sel ? s1code : s2code)[t * NB + b];
                float v = 0.f;
                if (c >= 1000)   v = redc[((size_t)(c - 1000) * NB + b) * DN + j];
                else if (c >= 0) v = bufc[((size_t)b * LN + c) * DN + j];
                cellv[sel][bl_][jj] = v;
            }
        }
        __syncthreads();

        // ============ concurrent GEMMs ============
        // reduce steps: waves 0-3 P1 (full 28 iters), waves 4-7 P2 s-part.
        // shift  steps: all 8 waves P1 (14 iters each; slots 0..31 / 32..63).
        float acc[5][4];   // P2 accumulators live across sync A in registers
        if (w < 4 || !red) {
            int weff = w & 3, ihalf = w >> 2;          // ihalf=1 only when !red
            int c8 = lane & 7, kq = lane >> 3;
            int kbase = weff * 224;
            int i0 = red ? 0 : ihalf * 14;
            int ni = red ? 28 : 14;
            const uint4* wp = (const uint4*)WAb + ((size_t)(jg * 896 + kbase + kq) * 8) + c8;
            float a0[8], a1[8];
            #pragma unroll
            for (int cc = 0; cc < 8; ++cc) { a0[cc] = 0.f; a1[cc] = 0.f; }
            #pragma unroll 4
            for (int ii = 0; ii < ni; ++ii) {
                int i = i0 + ii;
                uint4 wv = wp[(size_t)i * 64];          // wave: 1KB contiguous
                int k = kbase + kq + i * 8;
                float x0 = xs[0][k], x1 = xs[1][k];
                float wf0 = bf2f(wv.x & 0xFFFF), wf1 = bf2f(wv.x >> 16);
                float wf2 = bf2f(wv.y & 0xFFFF), wf3 = bf2f(wv.y >> 16);
                float wf4 = bf2f(wv.z & 0xFFFF), wf5 = bf2f(wv.z >> 16);
                float wf6 = bf2f(wv.w & 0xFFFF), wf7 = bf2f(wv.w >> 16);
                a0[0] += x0 * wf0; a1[0] += x1 * wf0;
                a0[1] += x0 * wf1; a1[1] += x1 * wf1;
                a0[2] += x0 * wf2; a1[2] += x1 * wf2;
                a0[3] += x0 * wf3; a1[3] += x1 * wf3;
                a0[4] += x0 * wf4; a1[4] += x1 * wf4;
                a0[5] += x0 * wf5; a1[5] += x1 * wf5;
                a0[6] += x0 * wf6; a1[6] += x1 * wf6;
                a0[7] += x0 * wf7; a1[7] += x1 * wf7;
            }
            int slot = weff * 8 + kq + (red ? 0 : ihalf * 32);
            #pragma unroll
            for (int cc = 0; cc < 8; ++cc) {
                part1[0][c8 * 8 + cc][slot] = a0[cc];
                part1[1][c8 * 8 + cc][slot] = a1[cc];
            }
        } else {
            int t2 = tid - 256, jj = t2 & 15, ks = t2 >> 4;   // 16 j x 16 kslices
            #pragma unroll
            for (int g = 0; g < 5; ++g)
                #pragma unroll
                for (int b4 = 0; b4 < 4; ++b4) acc[g][b4] = 0.f;
            const uint4* wb = (const uint4*)WBb + ((size_t)(jgw * 640 + ks * 32) * 16) + jj;
            #pragma unroll 4
            for (int i = 0; i < 32; ++i) {
                uint4 wv = wb[(size_t)i * 16];          // 8 slots (5 real) = 16B
                float w0 = bf2f(wv.x & 0xFFFF), w1 = bf2f(wv.x >> 16);
                float w2 = bf2f(wv.y & 0xFFFF), w3 = bf2f(wv.y >> 16);
                float w4 = bf2f(wv.z & 0xFFFF);
                float x0 = xs2[0][ks][i], x1 = xs2[1][ks][i];
                float x2 = xs2[2][ks][i], x3 = xs2[3][ks][i];
                acc[0][0] += x0 * w0; acc[1][0] += x0 * w1; acc[2][0] += x0 * w2; acc[3][0] += x0 * w3; acc[4][0] += x0 * w4;
                acc[0][1] += x1 * w0; acc[1][1] += x1 * w1; acc[2][1] += x1 * w2; acc[3][1] += x1 * w3; acc[4][1] += x1 * w4;
                acc[0][2] += x2 * w0; acc[1][2] += x2 * w1; acc[2][2] += x2 * w2; acc[3][2] += x2 * w3; acc[4][2] += x2 * w4;
                acc[0][3] += x3 * w0; acc[1][3] += x3 * w1; acc[2][3] += x3 * w2; acc[3][3] += x3 * w3; acc[4][3] += x3 * w4;
            }
        }
        __syncthreads();

        // ============ P1 reduce + tracker LSTM ============
        if (tid < 128) {
            int b = tid & 1, col = tid >> 1;
            float s = 0.f;
            #pragma unroll
            for (int ks = 0; ks < 32; ++ks) s += part1[b][col][ks];
            if (!red) {
                #pragma unroll
                for (int ks = 32; ks < 64; ++ks) s += part1[b][col][ks];
            }
            if (t > 0) s += blA[jg * 64 + col];
            gsum[b][col] = s;
        }
        __syncthreads();
        if (tid < 32) {
            int bl_ = tid >> 4, jj = tid & 15;
            int b = bg1 * 2 + bl_;
            int j = jg * 16 + jj;
            float4 g4 = *(const float4*)&gsum[bl_][jj * 4];     // a,i,f,o
            float tco = tc[((size_t)par * NB + b) * TKN + j];
            float c2v = tanhf(g4.x) * sigf(g4.y) + sigf(g4.z) * tco;
            float h2 = sigf(g4.w) * tanhf(c2v);
            tc[((size_t)(par ^ 1) * NB + b) * TKN + j] = c2v;
            cohSt(&th[((size_t)(par ^ 1) * NB + b) * TKN + j], h2);
        }

        if (!red) {
            // shift step: only the 8 WGs of pair u exchange th2 — pair sync
            psync(slotsP, u, xcd, pph);
            continue;
        }
        qsync(slots, grp, qph);   // sync A: th2 visible within 16-WG group

        // ==== WT part: issue th2 loads early, hide latency under s-part stores ====
        float xreg;
        {
            int b4 = tid >> 7, kk = tid & 127;
            xreg = cohLd(&th[((size_t)(par ^ 1) * NB + bg2 * 4 + b4) * TKN + kk]);
        }
        if (w >= 4) {   // filler: store s-part partials while xst loads fly
            int t2 = tid - 256, jj = t2 & 15, ks = t2 >> 4;
            #pragma unroll
            for (int g = 0; g < 5; ++g)
                #pragma unroll
                for (int b4 = 0; b4 < 4; ++b4)
                    part2[ks][jj][g * 4 + b4] = acc[g][b4];
        }
        {
            int b4 = tid >> 7, kk = tid & 127;
            xst[b4][kk] = xreg;
        }
        __syncthreads();
        if (w >= 4) {
            int t2 = tid - 256, jj = t2 & 15, ks = t2 >> 4;
            float wt[5][4];
            #pragma unroll
            for (int g = 0; g < 5; ++g)
                #pragma unroll
                for (int b4 = 0; b4 < 4; ++b4) wt[g][b4] = 0.f;
            const uint4* wb = (const uint4*)WBb + ((size_t)(jgw * 640 + 512 + ks * 8) * 16) + jj;
            #pragma unroll
            for (int i = 0; i < 8; ++i) {
                uint4 wv = wb[(size_t)i * 16];
                float w0 = bf2f(wv.x & 0xFFFF), w1 = bf2f(wv.x >> 16);
                float w2 = bf2f(wv.y & 0xFFFF), w3 = bf2f(wv.y >> 16);
                float w4 = bf2f(wv.z & 0xFFFF);
                int kk2 = ks * 8 + i;
                float x0 = xst[0][kk2], x1 = xst[1][kk2], x2 = xst[2][kk2], x3 = xst[3][kk2];
                wt[0][0] += x0 * w0; wt[1][0] += x0 * w1; wt[2][0] += x0 * w2; wt[3][0] += x0 * w3; wt[4][0] += x0 * w4;
                wt[0][1] += x1 * w0; wt[1][1] += x1 * w1; wt[2][1] += x1 * w2; wt[3][1] += x1 * w3; wt[4][1] += x1 * w4;
                wt[0][2] += x2 * w0; wt[1][2] += x2 * w1; wt[2][2] += x2 * w2; wt[3][2] += x2 * w3; wt[4][2] += x2 * w4;
                wt[0][3] += x3 * w0; wt[1][3] += x3 * w1; wt[2][3] += x3 * w2; wt[3][3] += x3 * w3; wt[4][3] += x3 * w4;
            }
            #pragma unroll
            for (int g = 0; g < 5; ++g)
                #pragma unroll
                for (int b4 = 0; b4 < 4; ++b4)
                    part2[ks][jj][g * 4 + b4] += wt[g][b4];
        }
        __syncthreads();
        if (tid < 320) {
            int g = tid >> 6, r = tid & 63;
            int bl_ = r >> 4, jj = r & 15;
            float s = 0.f;
            #pragma unroll
            for (int ks = 0; ks < 16; ++ks) s += part2[ks][jj][g * 4 + bl_];
            gsum2[bl_][g][jj] = s;
        }
        __syncthreads();
        if (tid < 64) {
            int bl_ = tid >> 4, jj = tid & 15;
            int b = bg2 * 4 + bl_;
            int wk = wkA[t * NB + b];
            if (wk >= 0) {
                int j = jgw * 16 + jj;
                float ga  = gsum2[bl_][0][jj] + bLv[0 * 256 + j];
                float gi  = gsum2[bl_][1][jj] + bLv[1 * 256 + j];
                float gf1 = gsum2[bl_][2][jj] + bLv[2 * 256 + j];
                float gf2 = gsum2[bl_][3][jj] + bLv[3 * 256 + j];
                float go  = gsum2[bl_][4][jj] + bLv[4 * 256 + j];
                float s2cv = cellv[0][bl_][jj];   // prefetched at staging
                float s1cv = cellv[1][bl_][jj];
                float cc = tanhf(ga) * sigf(gi) + sigf(gf1) * s2cv + sigf(gf2) * s1cv;
                float hh = sigf(go) * tanhf(cc);
                cohSt(&redh[((size_t)wk * NB + b) * DN + j], hh);   // cross-WG
                redc[((size_t)wk * NB + b) * DN + j] = cc;          // owner-stable
            }
        }
        qsync(slots, grp, qph);   // sync C: redh visible within 16-WG group
    }

    // ===== final output: P2-owner (b,j) writes its slice =====
    if (tid < 64) {
        int bl_ = tid >> 4, jj = tid & 15;
        int b = bg2 * 4 + bl_;
        int j = jgw * 16 + jj;
        int c = fcode[b];
        float h = 0.f, cv = 0.f;
        if (c >= 1000) {
            h  = cohLd(&redh[((size_t)(c - 1000) * NB + b) * DN + j]);
            cv = redc[((size_t)(c - 1000) * NB + b) * DN + j];
        } else if (c >= 0) {
            h  = bufh[((size_t)b * LN + c) * DN + j];
            cv = bufc[((size_t)b * LN + c) * DN + j];
        }
        out[(size_t)b * 2 * DN + j]      = h;
        out[(size_t)b * 2 * DN + DN + j] = cv;
    }
}

extern "C" void kernel_launch(void* const* d_in, const int* in_sizes, int n_in,
                              void* d_out, int out_size, void* d_ws, size_t ws_size,
                              hipStream_t stream) {
    const float* bufh = (const float*)d_in[0];
    const float* bufc = (const float*)d_in[1];
    const float* Wb   = (const float*)d_in[2];
    const float* W1   = (const float*)d_in[3];
    const float* W2   = (const float*)d_in[4];
    const float* Wl   = (const float*)d_in[5];
    const float* blv  = (const float*)d_in[6];
    const float* WLm  = (const float*)d_in[7];
    const float* bLv  = (const float*)d_in[8];
    const float* WR   = (const float*)d_in[9];
    const float* WT   = (const float*)d_in[10];
    const int* trans  = (const int*)d_in[11];
    float* out = (float*)d_out;

    char* p = (char*)d_ws;
    auto carve = [&](size_t bytes) -> char* {
        char* r = p;
        p += (bytes + 255) & ~(size_t)255;
        return r;
    };
    int* tbcode = (int*)carve((size_t)TN * NB * 4);
    int* s1code = (int*)carve((size_t)TN * NB * 4);
    int* s2code = (int*)carve((size_t)TN * NB * 4);
    int* wkA    = (int*)carve((size_t)TN * NB * 4);
    int* fcode  = (int*)carve((size_t)NB * 4);
    int* anyred = (int*)carve((size_t)TN * 4);
    float* th   = (float*)carve((size_t)2 * NB * TKN * 4);
    float* tc   = (float*)carve((size_t)2 * NB * TKN * 4);
    float* redh = (float*)carve((size_t)RMAX * NB * DN * 4);
    float* redc = (float*)carve((size_t)RMAX * NB * DN * 4);
    unsigned short* WAb = (unsigned short*)carve((size_t)8 * 896 * 64 * 2);
    float* blA  = (float*)carve((size_t)512 * 4);
    unsigned short* WBb = (unsigned short*)carve((size_t)16 * 640 * 128 * 2);
    unsigned* slots  = (unsigned*)carve((size_t)NWG * 16 * 4);
    unsigned* slotsP = (unsigned*)carve((size_t)NWG * 16 * 4);

    hipMemsetAsync(th, 0, (size_t)2 * NB * TKN * 4, stream);
    hipMemsetAsync(tc, 0, (size_t)2 * NB * TKN * 4, stream);
    hipMemsetAsync(slots, 0, (size_t)NWG * 16 * 4, stream);
    hipMemsetAsync(slotsP, 0, (size_t)NWG * 16 * 4, stream);

    k_sched<<<1, 64, 0, stream>>>(trans, tbcode, s1code, s2code, wkA, fcode, anyred);
    k_pack_a<<<(8 * 896 * 64 + 255) / 256, 256, 0, stream>>>(Wb, W1, W2, Wl, blv, WAb, blA);
    k_pack_b<<<(16 * 640 * 128 + 255) / 256, 256, 0, stream>>>(WLm, WR, WT, WBb);
    k_spinn<<<NWG, NT, 0, stream>>>(bufh, bufc, WAb, blA, WBb, bLv,
                                    tbcode, s1code, s2code, wkA, fcode, anyred,
                                    th, tc, redh, redc, slots, slotsP, out);
}